// Round 1
// baseline (9040.589 us; speedup 1.0000x reference)
//
#include <hip/hip_runtime.h>
#include <cstdint>

#define N_N 100000
#define N_E 1600000
#define HID 128
#define N_G 100
#define EPSF 1e-5f

static inline int ceil_div(int a, int b){ return (a + b - 1) / b; }

// ---------------- preprocessing ----------------

__global__ void k_init(float* __restrict__ deg, float* __restrict__ counts){
  int i = blockIdx.x * 256 + threadIdx.x;
  if (i < N_N) deg[i] = 1.0f;           // self-loop weight
  if (i < N_G) counts[i] = 0.0f;
}

__global__ void k_deg(const int* __restrict__ dst, const float* __restrict__ w,
                      float* __restrict__ deg){
  int e = blockIdx.x * 256 + threadIdx.x;
  if (e < N_E) atomicAdd(&deg[dst[e]], w[e]);
}

__global__ void k_counts(const int* __restrict__ bp, float* __restrict__ counts){
  int i = blockIdx.x * 256 + threadIdx.x;
  if (i < N_N) atomicAdd(&counts[bp[i]], 1.0f);
}

__global__ void k_dis(float* __restrict__ deg, float* __restrict__ nself){
  int i = blockIdx.x * 256 + threadIdx.x;
  if (i < N_N){
    float d = deg[i];
    float r = d > 0.f ? rsqrtf(d) : 0.f;
    deg[i] = r;            // deg becomes dis
    nself[i] = r * r;      // self-loop norm
  }
}

__global__ void k_norm(const int* __restrict__ src, const int* __restrict__ dst,
                       const float* __restrict__ w, const float* __restrict__ dis,
                       float* __restrict__ ne){
  int e = blockIdx.x * 256 + threadIdx.x;
  if (e < N_E) ne[e] = dis[src[e]] * w[e] * dis[dst[e]];
}

// ---------------- GEMM: H = X @ W, X: nrows x 128, W: 128 x 128 ----------------
// 64-row tile per block, 256 threads, each thread computes 4 rows x 8 cols.
__global__ __launch_bounds__(256) void k_gemm(const float* __restrict__ X,
                                              const float* __restrict__ W,
                                              float* __restrict__ H, int nrows){
  __shared__ float lA[64][33];    // +1 pad: kills 4-way bank conflict on column reads
  __shared__ float lW[32][128];
  int tid = threadIdx.x;
  int row0 = blockIdx.x * 64;
  int tx = tid & 15;              // feature group: cols tx*8 .. tx*8+7
  int ty = tid >> 4;              // row group: rows ty*4 .. ty*4+3

  float acc[4][8];
  #pragma unroll
  for (int i = 0; i < 4; ++i)
    #pragma unroll
    for (int j = 0; j < 8; ++j) acc[i][j] = 0.f;

  for (int kc = 0; kc < 128; kc += 32){
    // stage A chunk: 64 rows x 32 k  (512 float4, 2 per thread)
    #pragma unroll
    for (int it = 0; it < 2; ++it){
      int idx = tid + it * 256;
      int r = idx >> 3;
      int c4 = (idx & 7) * 4;
      float4 v = make_float4(0.f, 0.f, 0.f, 0.f);
      int gr = row0 + r;
      if (gr < nrows) v = *(const float4*)(X + (size_t)gr * HID + kc + c4);
      lA[r][c4 + 0] = v.x; lA[r][c4 + 1] = v.y;
      lA[r][c4 + 2] = v.z; lA[r][c4 + 3] = v.w;
    }
    // stage W chunk: 32 k x 128 cols (1024 float4, 4 per thread)
    #pragma unroll
    for (int it = 0; it < 4; ++it){
      int idx = tid + it * 256;
      int r = idx >> 5;
      int c4 = (idx & 31) * 4;
      *(float4*)&lW[r][c4] = *(const float4*)(W + (size_t)(kc + r) * HID + c4);
    }
    __syncthreads();
    #pragma unroll
    for (int k = 0; k < 32; ++k){
      float4 w0 = *(float4*)&lW[k][tx * 8];
      float4 w1 = *(float4*)&lW[k][tx * 8 + 4];
      #pragma unroll
      for (int i = 0; i < 4; ++i){
        float a = lA[ty * 4 + i][k];
        acc[i][0] += a * w0.x; acc[i][1] += a * w0.y;
        acc[i][2] += a * w0.z; acc[i][3] += a * w0.w;
        acc[i][4] += a * w1.x; acc[i][5] += a * w1.y;
        acc[i][6] += a * w1.z; acc[i][7] += a * w1.w;
      }
    }
    __syncthreads();
  }
  #pragma unroll
  for (int i = 0; i < 4; ++i){
    int gr = row0 + ty * 4 + i;
    if (gr < nrows){
      float* o = H + (size_t)gr * HID + tx * 8;
      *(float4*)o       = make_float4(acc[i][0], acc[i][1], acc[i][2], acc[i][3]);
      *(float4*)(o + 4) = make_float4(acc[i][4], acc[i][5], acc[i][6], acc[i][7]);
    }
  }
}

// ---------------- aggregation ----------------

// agg[i][f] = nself[i]*h[i][f] + bias[f]   (float4 over feature dim)
__global__ void k_agg_init(const float* __restrict__ h, const float* __restrict__ nself,
                           const float* __restrict__ bias, float* __restrict__ agg){
  int idx = blockIdx.x * 256 + threadIdx.x;
  if (idx >= N_N * 32) return;
  int i = idx >> 5, q = idx & 31;
  float ns = nself[i];
  float4 hv = ((const float4*)h)[idx];
  float4 bv = ((const float4*)bias)[q];
  float4 r;
  r.x = ns * hv.x + bv.x; r.y = ns * hv.y + bv.y;
  r.z = ns * hv.z + bv.z; r.w = ns * hv.w + bv.w;
  ((float4*)agg)[idx] = r;
}

// 32 lanes per edge, each lane handles a float4 of the 128-wide row
__global__ __launch_bounds__(256) void k_scatter(const int* __restrict__ src,
                                                 const int* __restrict__ dst,
                                                 const float* __restrict__ ne,
                                                 const float* __restrict__ h,
                                                 float* __restrict__ agg){
  int t = blockIdx.x * 256 + threadIdx.x;
  int e = t >> 5;
  if (e >= N_E) return;
  int lane = t & 31;
  float nv = ne[e];
  int s = src[e], d = dst[e];
  float4 hv = *(const float4*)(h + (size_t)s * HID + lane * 4);
  float* ap = agg + (size_t)d * HID + lane * 4;
  atomicAdd(ap + 0, nv * hv.x);
  atomicAdd(ap + 1, nv * hv.y);
  atomicAdd(ap + 2, nv * hv.z);
  atomicAdd(ap + 3, nv * hv.w);
}

// ---------------- GraphNorm ----------------

__global__ void k_zero2(float* __restrict__ a, float* __restrict__ b){
  int i = blockIdx.x * 256 + threadIdx.x;
  if (i < N_G * HID){ a[i] = 0.f; b[i] = 0.f; }
}

// per-graph sums exploiting sorted batch_ptr: 64-row runs, flush on graph change
__global__ __launch_bounds__(128) void k_gsum(const float* __restrict__ agg,
                                              const int* __restrict__ bp,
                                              float* __restrict__ mean){
  int f = threadIdx.x;
  int r0 = blockIdx.x * 64;
  int r1 = min(r0 + 64, N_N);
  int curg = bp[r0];
  float acc = 0.f;
  for (int r = r0; r < r1; ++r){
    int g = bp[r];
    if (g != curg){ atomicAdd(&mean[curg * HID + f], acc); acc = 0.f; curg = g; }
    acc += agg[(size_t)r * HID + f];
  }
  atomicAdd(&mean[curg * HID + f], acc);
}

__global__ void k_finmean(float* __restrict__ mean, const float* __restrict__ counts){
  int i = blockIdx.x * 256 + threadIdx.x;
  if (i < N_G * HID){
    float c = counts[i >> 7];
    mean[i] = c > 0.f ? mean[i] / c : 0.f;
  }
}

__global__ __launch_bounds__(128) void k_gvar(const float* __restrict__ agg,
                                              const int* __restrict__ bp,
                                              const float* __restrict__ mean,
                                              const float* __restrict__ alpha,
                                              float* __restrict__ var){
  int f = threadIdx.x;
  float al = alpha[f];
  int r0 = blockIdx.x * 64;
  int r1 = min(r0 + 64, N_N);
  int curg = bp[r0];
  float am = al * mean[curg * HID + f];
  float acc = 0.f;
  for (int r = r0; r < r1; ++r){
    int g = bp[r];
    if (g != curg){
      atomicAdd(&var[curg * HID + f], acc);
      acc = 0.f; curg = g; am = al * mean[curg * HID + f];
    }
    float v = agg[(size_t)r * HID + f] - am;
    acc += v * v;
  }
  atomicAdd(&var[curg * HID + f], acc);
}

__global__ void k_finvar(float* __restrict__ var, const float* __restrict__ counts){
  int i = blockIdx.x * 256 + threadIdx.x;
  if (i < N_G * HID){
    float c = counts[i >> 7];
    float v = c > 0.f ? var[i] / c : 0.f;
    var[i] = rsqrtf(v + EPSF);   // var becomes rstd
  }
}

__global__ void k_out(const float* __restrict__ agg, const int* __restrict__ bp,
                      const float* __restrict__ mean, const float* __restrict__ rstd,
                      const float* __restrict__ alpha, const float* __restrict__ gw,
                      const float* __restrict__ gb, float* __restrict__ out){
  int idx = blockIdx.x * 256 + threadIdx.x;
  if (idx >= N_N * 32) return;
  int i = idx >> 5, q = idx & 31;
  int g = bp[i];
  float4 a  = ((const float4*)agg)[idx];
  float4 m  = ((const float4*)mean)[g * 32 + q];
  float4 r  = ((const float4*)rstd)[g * 32 + q];
  float4 al = ((const float4*)alpha)[q];
  float4 wv = ((const float4*)gw)[q];
  float4 bv = ((const float4*)gb)[q];
  float4 o;
  o.x = fmaxf(wv.x * (a.x - al.x * m.x) * r.x + bv.x, 0.f);
  o.y = fmaxf(wv.y * (a.y - al.y * m.y) * r.y + bv.y, 0.f);
  o.z = fmaxf(wv.z * (a.z - al.z * m.z) * r.z + bv.z, 0.f);
  o.w = fmaxf(wv.w * (a.w - al.w * m.w) * r.w + bv.w, 0.f);
  ((float4*)out)[idx] = o;
}

// ---------------- launch ----------------

extern "C" void kernel_launch(void* const* d_in, const int* in_sizes, int n_in,
                              void* d_out, int out_size, void* d_ws, size_t ws_size,
                              hipStream_t stream){
  const float* node0 = (const float*)d_in[0];
  const int*   eidx  = (const int*)d_in[1];
  const float* eattr = (const float*)d_in[2];
  const int*   bp    = (const int*)d_in[3];
  const float* W     = (const float*)d_in[4];
  const float* bias  = (const float*)d_in[5];
  const float* gw    = (const float*)d_in[6];
  const float* gb    = (const float*)d_in[7];
  const float* ga    = (const float*)d_in[8];
  float* out = (float*)d_out;
  const int* src = eidx;
  const int* dst = eidx + N_E;

  char* p = (char*)d_ws;
  auto carve = [&](size_t nbytes) -> char* {
    char* q = p; p += (nbytes + 255) & ~(size_t)255; return q;
  };
  float* deg    = (float*)carve((size_t)N_N * 4);          // becomes dis
  float* nself  = (float*)carve((size_t)N_N * 4);
  float* counts = (float*)carve((size_t)N_G * 4);
  float* ne     = (float*)carve((size_t)N_E * 4);
  float* h      = (float*)carve((size_t)N_N * HID * 4);
  float* agg    = (float*)carve((size_t)N_N * HID * 4);
  float* mean   = (float*)carve((size_t)N_G * HID * 4);
  float* var    = (float*)carve((size_t)N_G * HID * 4);

  k_init  <<<ceil_div(N_N, 256), 256, 0, stream>>>(deg, counts);
  k_deg   <<<ceil_div(N_E, 256), 256, 0, stream>>>(dst, eattr, deg);
  k_counts<<<ceil_div(N_N, 256), 256, 0, stream>>>(bp, counts);
  k_dis   <<<ceil_div(N_N, 256), 256, 0, stream>>>(deg, nself);
  k_norm  <<<ceil_div(N_E, 256), 256, 0, stream>>>(src, dst, eattr, deg, ne);

  for (int l = 0; l < 3; ++l){
    const float* X = (l == 0) ? node0 : out;
    k_gemm    <<<ceil_div(N_N, 64), 256, 0, stream>>>(X, W + (size_t)l * HID * HID, h, N_N);
    k_agg_init<<<ceil_div(N_N * 32, 256), 256, 0, stream>>>(h, nself, bias + l * HID, agg);
    k_scatter <<<(N_E * 32) / 256, 256, 0, stream>>>(src, dst, ne, h, agg);
    k_zero2   <<<ceil_div(N_G * HID, 256), 256, 0, stream>>>(mean, var);
    k_gsum    <<<ceil_div(N_N, 64), 128, 0, stream>>>(agg, bp, mean);
    k_finmean <<<ceil_div(N_G * HID, 256), 256, 0, stream>>>(mean, counts);
    k_gvar    <<<ceil_div(N_N, 64), 128, 0, stream>>>(agg, bp, mean, ga + l * HID, var);
    k_finvar  <<<ceil_div(N_G * HID, 256), 256, 0, stream>>>(var, counts);
    k_out     <<<ceil_div(N_N * 32, 256), 256, 0, stream>>>(agg, bp, mean, var,
                 ga + l * HID, gw + l * HID, gb + l * HID, out);
  }
}

// Round 2
// 1461.436 us; speedup vs baseline: 6.1861x; 6.1861x over previous
//
#include <hip/hip_runtime.h>
#include <cstdint>

#define N_N 100000
#define N_E 1600000
#define HID 128
#define N_G 100
#define EPSF 1e-5f

static inline int ceil_div(int a, int b){ return (a + b - 1) / b; }

// ---------------- preprocessing ----------------

__global__ void k_init(float* __restrict__ deg, int* __restrict__ degi,
                       float* __restrict__ counts){
  int i = blockIdx.x * 256 + threadIdx.x;
  if (i < N_N){ deg[i] = 1.0f; degi[i] = 0; }   // self-loop weight 1
  if (i < N_G) counts[i] = 0.0f;
}

__global__ void k_deg(const int* __restrict__ dst, const float* __restrict__ w,
                      float* __restrict__ deg, int* __restrict__ degi){
  int e = blockIdx.x * 256 + threadIdx.x;
  if (e < N_E){
    int d = dst[e];
    atomicAdd(&deg[d], w[e]);
    atomicAdd(&degi[d], 1);
  }
}

__global__ void k_counts(const int* __restrict__ bp, float* __restrict__ counts){
  int i = blockIdx.x * 256 + threadIdx.x;
  if (i < N_N) atomicAdd(&counts[bp[i]], 1.0f);
}

__global__ void k_dis(float* __restrict__ deg, float* __restrict__ nself){
  int i = blockIdx.x * 256 + threadIdx.x;
  if (i < N_N){
    float d = deg[i];
    float r = d > 0.f ? rsqrtf(d) : 0.f;
    deg[i] = r;            // deg becomes dis
    nself[i] = r * r;      // self-loop norm
  }
}

// ---------------- CSR build: exclusive scan of degi -> ptr ----------------

__global__ __launch_bounds__(256) void k_scanA(const int* __restrict__ degi,
                                               int* __restrict__ partial,
                                               int* __restrict__ bsum){
  __shared__ int s[256];
  int t = threadIdx.x;
  int i = blockIdx.x * 256 + t;
  int v = (i < N_N) ? degi[i] : 0;
  s[t] = v; __syncthreads();
  #pragma unroll
  for (int off = 1; off < 256; off <<= 1){
    int tmp = (t >= off) ? s[t - off] : 0;
    __syncthreads();
    s[t] += tmp;
    __syncthreads();
  }
  if (i < N_N) partial[i] = s[t] - v;     // exclusive within block
  if (t == 255) bsum[blockIdx.x] = s[255];
}

__global__ __launch_bounds__(512) void k_scanB(int* __restrict__ bsum, int nblocks){
  __shared__ int s[512];
  int t = threadIdx.x;
  int v = (t < nblocks) ? bsum[t] : 0;
  s[t] = v; __syncthreads();
  #pragma unroll
  for (int off = 1; off < 512; off <<= 1){
    int tmp = (t >= off) ? s[t - off] : 0;
    __syncthreads();
    s[t] += tmp;
    __syncthreads();
  }
  if (t < nblocks) bsum[t] = s[t] - v;    // exclusive block offsets
}

__global__ void k_scanC(const int* __restrict__ partial, const int* __restrict__ bsum,
                        int* __restrict__ ptr, int* __restrict__ cursor){
  int i = blockIdx.x * 256 + threadIdx.x;
  if (i < N_N){
    int p = partial[i] + bsum[blockIdx.x];
    ptr[i] = p; cursor[i] = p;
  }
  if (i == 0) ptr[N_N] = N_E;
}

// fill sorted edge arrays; fuse norm computation
__global__ void k_fill(const int* __restrict__ src, const int* __restrict__ dst,
                       const float* __restrict__ w, const float* __restrict__ dis,
                       int* __restrict__ cursor, int* __restrict__ src_s,
                       float* __restrict__ ne_s){
  int e = blockIdx.x * 256 + threadIdx.x;
  if (e < N_E){
    int d = dst[e], s = src[e];
    int slot = atomicAdd(&cursor[d], 1);
    src_s[slot] = s;
    ne_s[slot] = dis[s] * w[e] * dis[d];
  }
}

// ---------------- GEMM: H = X @ W, X: nrows x 128, W: 128 x 128 ----------------
__global__ __launch_bounds__(256) void k_gemm(const float* __restrict__ X,
                                              const float* __restrict__ W,
                                              float* __restrict__ H, int nrows){
  __shared__ float lA[64][33];
  __shared__ float lW[32][128];
  int tid = threadIdx.x;
  int row0 = blockIdx.x * 64;
  int tx = tid & 15;
  int ty = tid >> 4;

  float acc[4][8];
  #pragma unroll
  for (int i = 0; i < 4; ++i)
    #pragma unroll
    for (int j = 0; j < 8; ++j) acc[i][j] = 0.f;

  for (int kc = 0; kc < 128; kc += 32){
    #pragma unroll
    for (int it = 0; it < 2; ++it){
      int idx = tid + it * 256;
      int r = idx >> 3;
      int c4 = (idx & 7) * 4;
      float4 v = make_float4(0.f, 0.f, 0.f, 0.f);
      int gr = row0 + r;
      if (gr < nrows) v = *(const float4*)(X + (size_t)gr * HID + kc + c4);
      lA[r][c4 + 0] = v.x; lA[r][c4 + 1] = v.y;
      lA[r][c4 + 2] = v.z; lA[r][c4 + 3] = v.w;
    }
    #pragma unroll
    for (int it = 0; it < 4; ++it){
      int idx = tid + it * 256;
      int r = idx >> 5;
      int c4 = (idx & 31) * 4;
      *(float4*)&lW[r][c4] = *(const float4*)(W + (size_t)(kc + r) * HID + c4);
    }
    __syncthreads();
    #pragma unroll
    for (int k = 0; k < 32; ++k){
      float4 w0 = *(float4*)&lW[k][tx * 8];
      float4 w1 = *(float4*)&lW[k][tx * 8 + 4];
      #pragma unroll
      for (int i = 0; i < 4; ++i){
        float a = lA[ty * 4 + i][k];
        acc[i][0] += a * w0.x; acc[i][1] += a * w0.y;
        acc[i][2] += a * w0.z; acc[i][3] += a * w0.w;
        acc[i][4] += a * w1.x; acc[i][5] += a * w1.y;
        acc[i][6] += a * w1.z; acc[i][7] += a * w1.w;
      }
    }
    __syncthreads();
  }
  #pragma unroll
  for (int i = 0; i < 4; ++i){
    int gr = row0 + ty * 4 + i;
    if (gr < nrows){
      float* o = H + (size_t)gr * HID + tx * 8;
      *(float4*)o       = make_float4(acc[i][0], acc[i][1], acc[i][2], acc[i][3]);
      *(float4*)(o + 4) = make_float4(acc[i][4], acc[i][5], acc[i][6], acc[i][7]);
    }
  }
}

// ---------------- gather aggregation (no atomics) ----------------
// 32 lanes per node; lane covers float4 of the 128-wide row.
// agg[i] = nself[i]*h[i] + bias + sum_e ne_s[e]*h[src_s[e]]
__global__ __launch_bounds__(256) void k_gather(const int* __restrict__ ptr,
                                                const int* __restrict__ src_s,
                                                const float* __restrict__ ne_s,
                                                const float* __restrict__ h,
                                                const float* __restrict__ nself,
                                                const float* __restrict__ bias,
                                                float* __restrict__ agg){
  int t = blockIdx.x * 256 + threadIdx.x;
  int node = t >> 5;
  if (node >= N_N) return;
  int lane = t & 31;
  const float4* h4 = (const float4*)h;
  float ns = nself[node];
  float4 hv = h4[(size_t)node * 32 + lane];
  float4 bv = ((const float4*)bias)[lane];
  float4 acc;
  acc.x = ns * hv.x + bv.x; acc.y = ns * hv.y + bv.y;
  acc.z = ns * hv.z + bv.z; acc.w = ns * hv.w + bv.w;
  int e0 = ptr[node], e1 = ptr[node + 1];
  for (int e = e0; e < e1; ++e){
    int s = src_s[e];
    float nv = ne_s[e];
    float4 sv = h4[(size_t)s * 32 + lane];
    acc.x += nv * sv.x; acc.y += nv * sv.y;
    acc.z += nv * sv.z; acc.w += nv * sv.w;
  }
  ((float4*)agg)[(size_t)node * 32 + lane] = acc;
}

// ---------------- GraphNorm (single-pass stats) ----------------

__global__ void k_zero2(float* __restrict__ a, float* __restrict__ b){
  int i = blockIdx.x * 256 + threadIdx.x;
  if (i < N_G * HID){ a[i] = 0.f; b[i] = 0.f; }
}

// per-graph sum & sumsq exploiting sorted batch_ptr: 64-row runs, flush on change
__global__ __launch_bounds__(128) void k_gstat(const float* __restrict__ agg,
                                               const int* __restrict__ bp,
                                               float* __restrict__ sum,
                                               float* __restrict__ sumsq){
  int f = threadIdx.x;
  int r0 = blockIdx.x * 64;
  int r1 = min(r0 + 64, N_N);
  int curg = bp[r0];
  float s = 0.f, s2 = 0.f;
  for (int r = r0; r < r1; ++r){
    int g = bp[r];
    if (g != curg){
      atomicAdd(&sum[curg * HID + f], s);
      atomicAdd(&sumsq[curg * HID + f], s2);
      s = 0.f; s2 = 0.f; curg = g;
    }
    float v = agg[(size_t)r * HID + f];
    s += v; s2 += v * v;
  }
  atomicAdd(&sum[curg * HID + f], s);
  atomicAdd(&sumsq[curg * HID + f], s2);
}

// mean = sum/c ; var = E[x^2] - m^2 * a*(2-a) ; rstd = rsqrt(var+eps)
__global__ void k_finstat(const float* __restrict__ sum, const float* __restrict__ sumsq,
                          const float* __restrict__ counts, const float* __restrict__ alpha,
                          float* __restrict__ mean, float* __restrict__ rstd){
  int i = blockIdx.x * 256 + threadIdx.x;
  if (i >= N_G * HID) return;
  int f = i & (HID - 1);
  float c = counts[i >> 7];
  float inv = c > 0.f ? 1.0f / c : 0.f;
  float m = sum[i] * inv;
  float ex2 = sumsq[i] * inv;
  float al = alpha[f];
  float var = ex2 - m * m * al * (2.0f - al);
  mean[i] = m;
  rstd[i] = rsqrtf(var + EPSF);
}

__global__ void k_out(const float* __restrict__ agg, const int* __restrict__ bp,
                      const float* __restrict__ mean, const float* __restrict__ rstd,
                      const float* __restrict__ alpha, const float* __restrict__ gw,
                      const float* __restrict__ gb, float* __restrict__ out){
  int idx = blockIdx.x * 256 + threadIdx.x;
  if (idx >= N_N * 32) return;
  int i = idx >> 5, q = idx & 31;
  int g = bp[i];
  float4 a  = ((const float4*)agg)[idx];
  float4 m  = ((const float4*)mean)[g * 32 + q];
  float4 r  = ((const float4*)rstd)[g * 32 + q];
  float4 al = ((const float4*)alpha)[q];
  float4 wv = ((const float4*)gw)[q];
  float4 bv = ((const float4*)gb)[q];
  float4 o;
  o.x = fmaxf(wv.x * (a.x - al.x * m.x) * r.x + bv.x, 0.f);
  o.y = fmaxf(wv.y * (a.y - al.y * m.y) * r.y + bv.y, 0.f);
  o.z = fmaxf(wv.z * (a.z - al.z * m.z) * r.z + bv.z, 0.f);
  o.w = fmaxf(wv.w * (a.w - al.w * m.w) * r.w + bv.w, 0.f);
  ((float4*)out)[idx] = o;
}

// ---------------- launch ----------------

extern "C" void kernel_launch(void* const* d_in, const int* in_sizes, int n_in,
                              void* d_out, int out_size, void* d_ws, size_t ws_size,
                              hipStream_t stream){
  const float* node0 = (const float*)d_in[0];
  const int*   eidx  = (const int*)d_in[1];
  const float* eattr = (const float*)d_in[2];
  const int*   bp    = (const int*)d_in[3];
  const float* W     = (const float*)d_in[4];
  const float* bias  = (const float*)d_in[5];
  const float* gw    = (const float*)d_in[6];
  const float* gb    = (const float*)d_in[7];
  const float* ga    = (const float*)d_in[8];
  float* out = (float*)d_out;
  const int* src = eidx;
  const int* dst = eidx + N_E;

  char* p = (char*)d_ws;
  auto carve = [&](size_t nbytes) -> char* {
    char* q = p; p += (nbytes + 255) & ~(size_t)255; return q;
  };
  float* deg    = (float*)carve((size_t)N_N * 4);          // becomes dis
  float* nself  = (float*)carve((size_t)N_N * 4);
  float* counts = (float*)carve((size_t)N_G * 4);
  int*   degi   = (int*)  carve((size_t)N_N * 4);
  int*   partial= (int*)  carve((size_t)N_N * 4);
  int*   bsum   = (int*)  carve((size_t)512 * 4);
  int*   ptr    = (int*)  carve((size_t)(N_N + 1) * 4);
  int*   cursor = (int*)  carve((size_t)N_N * 4);
  int*   src_s  = (int*)  carve((size_t)N_E * 4);
  float* ne_s   = (float*)carve((size_t)N_E * 4);
  float* h      = (float*)carve((size_t)N_N * HID * 4);
  float* agg    = (float*)carve((size_t)N_N * HID * 4);
  float* mean   = (float*)carve((size_t)N_G * HID * 4);
  float* rstd   = (float*)carve((size_t)N_G * HID * 4);
  float* sum    = (float*)carve((size_t)N_G * HID * 4);
  float* sumsq  = (float*)carve((size_t)N_G * HID * 4);

  int nblocks = ceil_div(N_N, 256);   // 391

  k_init  <<<nblocks, 256, 0, stream>>>(deg, degi, counts);
  k_deg   <<<ceil_div(N_E, 256), 256, 0, stream>>>(dst, eattr, deg, degi);
  k_counts<<<nblocks, 256, 0, stream>>>(bp, counts);
  k_dis   <<<nblocks, 256, 0, stream>>>(deg, nself);
  k_scanA <<<nblocks, 256, 0, stream>>>(degi, partial, bsum);
  k_scanB <<<1, 512, 0, stream>>>(bsum, nblocks);
  k_scanC <<<nblocks, 256, 0, stream>>>(partial, bsum, ptr, cursor);
  k_fill  <<<ceil_div(N_E, 256), 256, 0, stream>>>(src, dst, eattr, deg, cursor, src_s, ne_s);

  for (int l = 0; l < 3; ++l){
    const float* X = (l == 0) ? node0 : out;
    k_gemm   <<<ceil_div(N_N, 64), 256, 0, stream>>>(X, W + (size_t)l * HID * HID, h, N_N);
    k_gather <<<ceil_div(N_N * 32, 256), 256, 0, stream>>>(ptr, src_s, ne_s, h, nself,
                 bias + l * HID, agg);
    k_zero2  <<<ceil_div(N_G * HID, 256), 256, 0, stream>>>(sum, sumsq);
    k_gstat  <<<ceil_div(N_N, 64), 128, 0, stream>>>(agg, bp, sum, sumsq);
    k_finstat<<<ceil_div(N_G * HID, 256), 256, 0, stream>>>(sum, sumsq, counts,
                 ga + l * HID, mean, rstd);
    k_out    <<<ceil_div(N_N * 32, 256), 256, 0, stream>>>(agg, bp, mean, rstd,
                 ga + l * HID, gw + l * HID, gb + l * HID, out);
  }
}

// Round 3
// 1051.333 us; speedup vs baseline: 8.5992x; 1.3901x over previous
//
#include <hip/hip_runtime.h>
#include <cstdint>

#define N_N 100000
#define N_E 1600000
#define HID 128
#define N_G 100
#define EPSF 1e-5f

static inline int ceil_div(int a, int b){ return (a + b - 1) / b; }

// ---------------- preprocessing ----------------

__global__ void k_init(float* __restrict__ deg, int* __restrict__ degi,
                       float* __restrict__ counts){
  int i = blockIdx.x * 256 + threadIdx.x;
  if (i < N_N){ deg[i] = 1.0f; degi[i] = 0; }   // self-loop weight 1
  if (i < N_G) counts[i] = 0.0f;
}

__global__ void k_deg(const int* __restrict__ dst, const float* __restrict__ w,
                      float* __restrict__ deg, int* __restrict__ degi){
  int e = blockIdx.x * 256 + threadIdx.x;
  if (e < N_E){
    int d = dst[e];
    atomicAdd(&deg[d], w[e]);
    atomicAdd(&degi[d], 1);
  }
}

// counts via run-length over sorted batch_ptr: each thread scans 32 rows,
// flushes one atomic per graph boundary (~3K atomics vs 100K all-colliding).
__global__ void k_counts(const int* __restrict__ bp, float* __restrict__ counts){
  int t = blockIdx.x * 256 + threadIdx.x;
  int r0 = t * 32;
  if (r0 >= N_N) return;
  int r1 = min(r0 + 32, N_N);
  int curg = bp[r0];
  float acc = 0.f;
  for (int r = r0; r < r1; ++r){
    int g = bp[r];
    if (g != curg){ atomicAdd(&counts[curg], acc); acc = 0.f; curg = g; }
    acc += 1.0f;
  }
  atomicAdd(&counts[curg], acc);
}

__global__ void k_dis(float* __restrict__ deg, float* __restrict__ nself){
  int i = blockIdx.x * 256 + threadIdx.x;
  if (i < N_N){
    float d = deg[i];
    float r = d > 0.f ? rsqrtf(d) : 0.f;
    deg[i] = r;            // deg becomes dis
    nself[i] = r * r;      // self-loop norm
  }
}

// ---------------- CSR build: exclusive scan of degi -> ptr ----------------

__global__ __launch_bounds__(256) void k_scanA(const int* __restrict__ degi,
                                               int* __restrict__ partial,
                                               int* __restrict__ bsum){
  __shared__ int s[256];
  int t = threadIdx.x;
  int i = blockIdx.x * 256 + t;
  int v = (i < N_N) ? degi[i] : 0;
  s[t] = v; __syncthreads();
  #pragma unroll
  for (int off = 1; off < 256; off <<= 1){
    int tmp = (t >= off) ? s[t - off] : 0;
    __syncthreads();
    s[t] += tmp;
    __syncthreads();
  }
  if (i < N_N) partial[i] = s[t] - v;     // exclusive within block
  if (t == 255) bsum[blockIdx.x] = s[255];
}

__global__ __launch_bounds__(512) void k_scanB(int* __restrict__ bsum, int nblocks){
  __shared__ int s[512];
  int t = threadIdx.x;
  int v = (t < nblocks) ? bsum[t] : 0;
  s[t] = v; __syncthreads();
  #pragma unroll
  for (int off = 1; off < 512; off <<= 1){
    int tmp = (t >= off) ? s[t - off] : 0;
    __syncthreads();
    s[t] += tmp;
    __syncthreads();
  }
  if (t < nblocks) bsum[t] = s[t] - v;    // exclusive block offsets
}

__global__ void k_scanC(const int* __restrict__ partial, const int* __restrict__ bsum,
                        int* __restrict__ ptr, int* __restrict__ cursor){
  int i = blockIdx.x * 256 + threadIdx.x;
  if (i < N_N){
    int p = partial[i] + bsum[blockIdx.x];
    ptr[i] = p; cursor[i] = p;
  }
  if (i == 0) ptr[N_N] = N_E;
}

// fill sorted edge arrays; fuse norm computation
__global__ void k_fill(const int* __restrict__ src, const int* __restrict__ dst,
                       const float* __restrict__ w, const float* __restrict__ dis,
                       int* __restrict__ cursor, int* __restrict__ src_s,
                       float* __restrict__ ne_s){
  int e = blockIdx.x * 256 + threadIdx.x;
  if (e < N_E){
    int d = dst[e], s = src[e];
    int slot = atomicAdd(&cursor[d], 1);
    src_s[slot] = s;
    ne_s[slot] = dis[s] * w[e] * dis[d];
  }
}

// ---------------- GEMM: H = X @ W, X: nrows x 128, W: 128 x 128 ----------------
__global__ __launch_bounds__(256) void k_gemm(const float* __restrict__ X,
                                              const float* __restrict__ W,
                                              float* __restrict__ H, int nrows){
  __shared__ float lA[64][33];
  __shared__ float lW[32][128];
  int tid = threadIdx.x;
  int row0 = blockIdx.x * 64;
  int tx = tid & 15;
  int ty = tid >> 4;

  float acc[4][8];
  #pragma unroll
  for (int i = 0; i < 4; ++i)
    #pragma unroll
    for (int j = 0; j < 8; ++j) acc[i][j] = 0.f;

  for (int kc = 0; kc < 128; kc += 32){
    #pragma unroll
    for (int it = 0; it < 2; ++it){
      int idx = tid + it * 256;
      int r = idx >> 3;
      int c4 = (idx & 7) * 4;
      float4 v = make_float4(0.f, 0.f, 0.f, 0.f);
      int gr = row0 + r;
      if (gr < nrows) v = *(const float4*)(X + (size_t)gr * HID + kc + c4);
      lA[r][c4 + 0] = v.x; lA[r][c4 + 1] = v.y;
      lA[r][c4 + 2] = v.z; lA[r][c4 + 3] = v.w;
    }
    #pragma unroll
    for (int it = 0; it < 4; ++it){
      int idx = tid + it * 256;
      int r = idx >> 5;
      int c4 = (idx & 31) * 4;
      *(float4*)&lW[r][c4] = *(const float4*)(W + (size_t)(kc + r) * HID + c4);
    }
    __syncthreads();
    #pragma unroll
    for (int k = 0; k < 32; ++k){
      float4 w0 = *(float4*)&lW[k][tx * 8];
      float4 w1 = *(float4*)&lW[k][tx * 8 + 4];
      #pragma unroll
      for (int i = 0; i < 4; ++i){
        float a = lA[ty * 4 + i][k];
        acc[i][0] += a * w0.x; acc[i][1] += a * w0.y;
        acc[i][2] += a * w0.z; acc[i][3] += a * w0.w;
        acc[i][4] += a * w1.x; acc[i][5] += a * w1.y;
        acc[i][6] += a * w1.z; acc[i][7] += a * w1.w;
      }
    }
    __syncthreads();
  }
  #pragma unroll
  for (int i = 0; i < 4; ++i){
    int gr = row0 + ty * 4 + i;
    if (gr < nrows){
      float* o = H + (size_t)gr * HID + tx * 8;
      *(float4*)o       = make_float4(acc[i][0], acc[i][1], acc[i][2], acc[i][3]);
      *(float4*)(o + 4) = make_float4(acc[i][4], acc[i][5], acc[i][6], acc[i][7]);
    }
  }
}

// ---------------- gather aggregation (no atomics) ----------------
__global__ __launch_bounds__(256) void k_gather(const int* __restrict__ ptr,
                                                const int* __restrict__ src_s,
                                                const float* __restrict__ ne_s,
                                                const float* __restrict__ h,
                                                const float* __restrict__ nself,
                                                const float* __restrict__ bias,
                                                float* __restrict__ agg){
  int t = blockIdx.x * 256 + threadIdx.x;
  int node = t >> 5;
  if (node >= N_N) return;
  int lane = t & 31;
  const float4* h4 = (const float4*)h;
  float ns = nself[node];
  float4 hv = h4[(size_t)node * 32 + lane];
  float4 bv = ((const float4*)bias)[lane];
  float4 acc;
  acc.x = ns * hv.x + bv.x; acc.y = ns * hv.y + bv.y;
  acc.z = ns * hv.z + bv.z; acc.w = ns * hv.w + bv.w;
  int e0 = ptr[node], e1 = ptr[node + 1];
  for (int e = e0; e < e1; ++e){
    int s = src_s[e];
    float nv = ne_s[e];
    float4 sv = h4[(size_t)s * 32 + lane];
    acc.x += nv * sv.x; acc.y += nv * sv.y;
    acc.z += nv * sv.z; acc.w += nv * sv.w;
  }
  ((float4*)agg)[(size_t)node * 32 + lane] = acc;
}

// ---------------- GraphNorm (single-pass stats) ----------------

__global__ void k_zero2(float* __restrict__ a, float* __restrict__ b){
  int i = blockIdx.x * 256 + threadIdx.x;
  if (i < N_G * HID){ a[i] = 0.f; b[i] = 0.f; }
}

__global__ __launch_bounds__(128) void k_gstat(const float* __restrict__ agg,
                                               const int* __restrict__ bp,
                                               float* __restrict__ sum,
                                               float* __restrict__ sumsq){
  int f = threadIdx.x;
  int r0 = blockIdx.x * 64;
  int r1 = min(r0 + 64, N_N);
  int curg = bp[r0];
  float s = 0.f, s2 = 0.f;
  for (int r = r0; r < r1; ++r){
    int g = bp[r];
    if (g != curg){
      atomicAdd(&sum[curg * HID + f], s);
      atomicAdd(&sumsq[curg * HID + f], s2);
      s = 0.f; s2 = 0.f; curg = g;
    }
    float v = agg[(size_t)r * HID + f];
    s += v; s2 += v * v;
  }
  atomicAdd(&sum[curg * HID + f], s);
  atomicAdd(&sumsq[curg * HID + f], s2);
}

// mean = sum/c ; var = E[x^2] - m^2 * a*(2-a) ; rstd = rsqrt(var+eps)
__global__ void k_finstat(const float* __restrict__ sum, const float* __restrict__ sumsq,
                          const float* __restrict__ counts, const float* __restrict__ alpha,
                          float* __restrict__ mean, float* __restrict__ rstd){
  int i = blockIdx.x * 256 + threadIdx.x;
  if (i >= N_G * HID) return;
  int f = i & (HID - 1);
  float c = counts[i >> 7];
  float inv = c > 0.f ? 1.0f / c : 0.f;
  float m = sum[i] * inv;
  float ex2 = sumsq[i] * inv;
  float al = alpha[f];
  float var = ex2 - m * m * al * (2.0f - al);
  mean[i] = m;
  rstd[i] = rsqrtf(var + EPSF);
}

__global__ void k_out(const float* __restrict__ agg, const int* __restrict__ bp,
                      const float* __restrict__ mean, const float* __restrict__ rstd,
                      const float* __restrict__ alpha, const float* __restrict__ gw,
                      const float* __restrict__ gb, float* __restrict__ out){
  int idx = blockIdx.x * 256 + threadIdx.x;
  if (idx >= N_N * 32) return;
  int i = idx >> 5, q = idx & 31;
  int g = bp[i];
  float4 a  = ((const float4*)agg)[idx];
  float4 m  = ((const float4*)mean)[g * 32 + q];
  float4 r  = ((const float4*)rstd)[g * 32 + q];
  float4 al = ((const float4*)alpha)[q];
  float4 wv = ((const float4*)gw)[q];
  float4 bv = ((const float4*)gb)[q];
  float4 o;
  o.x = fmaxf(wv.x * (a.x - al.x * m.x) * r.x + bv.x, 0.f);
  o.y = fmaxf(wv.y * (a.y - al.y * m.y) * r.y + bv.y, 0.f);
  o.z = fmaxf(wv.z * (a.z - al.z * m.z) * r.z + bv.z, 0.f);
  o.w = fmaxf(wv.w * (a.w - al.w * m.w) * r.w + bv.w, 0.f);
  ((float4*)out)[idx] = o;
}

// ---------------- launch ----------------

extern "C" void kernel_launch(void* const* d_in, const int* in_sizes, int n_in,
                              void* d_out, int out_size, void* d_ws, size_t ws_size,
                              hipStream_t stream){
  const float* node0 = (const float*)d_in[0];
  const int*   eidx  = (const int*)d_in[1];
  const float* eattr = (const float*)d_in[2];
  const int*   bp    = (const int*)d_in[3];
  const float* W     = (const float*)d_in[4];
  const float* bias  = (const float*)d_in[5];
  const float* gw    = (const float*)d_in[6];
  const float* gb    = (const float*)d_in[7];
  const float* ga    = (const float*)d_in[8];
  float* out = (float*)d_out;
  const int* src = eidx;
  const int* dst = eidx + N_E;

  char* p = (char*)d_ws;
  auto carve = [&](size_t nbytes) -> char* {
    char* q = p; p += (nbytes + 255) & ~(size_t)255; return q;
  };
  float* deg    = (float*)carve((size_t)N_N * 4);          // becomes dis
  float* nself  = (float*)carve((size_t)N_N * 4);
  float* counts = (float*)carve((size_t)N_G * 4);
  int*   degi   = (int*)  carve((size_t)N_N * 4);
  int*   partial= (int*)  carve((size_t)N_N * 4);
  int*   bsum   = (int*)  carve((size_t)512 * 4);
  int*   ptr    = (int*)  carve((size_t)(N_N + 1) * 4);
  int*   cursor = (int*)  carve((size_t)N_N * 4);
  int*   src_s  = (int*)  carve((size_t)N_E * 4);
  float* ne_s   = (float*)carve((size_t)N_E * 4);
  float* h      = (float*)carve((size_t)N_N * HID * 4);
  float* agg    = (float*)carve((size_t)N_N * HID * 4);
  float* mean   = (float*)carve((size_t)N_G * HID * 4);
  float* rstd   = (float*)carve((size_t)N_G * HID * 4);
  float* sum    = (float*)carve((size_t)N_G * HID * 4);
  float* sumsq  = (float*)carve((size_t)N_G * HID * 4);

  int nblocks = ceil_div(N_N, 256);   // 391

  k_init  <<<nblocks, 256, 0, stream>>>(deg, degi, counts);
  k_deg   <<<ceil_div(N_E, 256), 256, 0, stream>>>(dst, eattr, deg, degi);
  k_counts<<<ceil_div(N_N, 32 * 256), 256, 0, stream>>>(bp, counts);
  k_dis   <<<nblocks, 256, 0, stream>>>(deg, nself);
  k_scanA <<<nblocks, 256, 0, stream>>>(degi, partial, bsum);
  k_scanB <<<1, 512, 0, stream>>>(bsum, nblocks);
  k_scanC <<<nblocks, 256, 0, stream>>>(partial, bsum, ptr, cursor);
  k_fill  <<<ceil_div(N_E, 256), 256, 0, stream>>>(src, dst, eattr, deg, cursor, src_s, ne_s);

  for (int l = 0; l < 3; ++l){
    const float* X = (l == 0) ? node0 : out;
    k_gemm   <<<ceil_div(N_N, 64), 256, 0, stream>>>(X, W + (size_t)l * HID * HID, h, N_N);
    k_gather <<<ceil_div(N_N * 32, 256), 256, 0, stream>>>(ptr, src_s, ne_s, h, nself,
                 bias + l * HID, agg);
    k_zero2  <<<ceil_div(N_G * HID, 256), 256, 0, stream>>>(sum, sumsq);
    k_gstat  <<<ceil_div(N_N, 64), 128, 0, stream>>>(agg, bp, sum, sumsq);
    k_finstat<<<ceil_div(N_G * HID, 256), 256, 0, stream>>>(sum, sumsq, counts,
                 ga + l * HID, mean, rstd);
    k_out    <<<ceil_div(N_N * 32, 256), 256, 0, stream>>>(agg, bp, mean, rstd,
                 ga + l * HID, gw + l * HID, gb + l * HID, out);
  }
}

// Round 4
// 991.397 us; speedup vs baseline: 9.1190x; 1.0605x over previous
//
#include <hip/hip_runtime.h>
#include <cstdint>

#define N_N 100000
#define N_E 1600000
#define HID 128
#define N_G 100
#define EPSF 1e-5f

static inline int ceil_div(int a, int b){ return (a + b - 1) / b; }

// ---------------- preprocessing ----------------

__global__ void k_init(int* __restrict__ degi, float* __restrict__ counts){
  int i = blockIdx.x * 256 + threadIdx.x;
  if (i < N_N) degi[i] = 0;
  if (i < N_G) counts[i] = 0.0f;
}

// count incoming edges per dst (int atomics only — deg float sum moved to k_dis)
__global__ void k_cnt(const int* __restrict__ dst, int* __restrict__ degi){
  int e = blockIdx.x * 256 + threadIdx.x;
  if (e < N_E) atomicAdd(&degi[dst[e]], 1);
}

// counts via run-length over sorted batch_ptr
__global__ void k_counts(const int* __restrict__ bp, float* __restrict__ counts){
  int t = blockIdx.x * 256 + threadIdx.x;
  int r0 = t * 32;
  if (r0 >= N_N) return;
  int r1 = min(r0 + 32, N_N);
  int curg = bp[r0];
  float acc = 0.f;
  for (int r = r0; r < r1; ++r){
    int g = bp[r];
    if (g != curg){ atomicAdd(&counts[curg], acc); acc = 0.f; curg = g; }
    acc += 1.0f;
  }
  atomicAdd(&counts[curg], acc);
}

// ---------------- CSR build: exclusive scan of degi -> ptr ----------------

__global__ __launch_bounds__(256) void k_scanA(const int* __restrict__ degi,
                                               int* __restrict__ partial,
                                               int* __restrict__ bsum){
  __shared__ int s[256];
  int t = threadIdx.x;
  int i = blockIdx.x * 256 + t;
  int v = (i < N_N) ? degi[i] : 0;
  s[t] = v; __syncthreads();
  #pragma unroll
  for (int off = 1; off < 256; off <<= 1){
    int tmp = (t >= off) ? s[t - off] : 0;
    __syncthreads();
    s[t] += tmp;
    __syncthreads();
  }
  if (i < N_N) partial[i] = s[t] - v;
  if (t == 255) bsum[blockIdx.x] = s[255];
}

__global__ __launch_bounds__(512) void k_scanB(int* __restrict__ bsum, int nblocks){
  __shared__ int s[512];
  int t = threadIdx.x;
  int v = (t < nblocks) ? bsum[t] : 0;
  s[t] = v; __syncthreads();
  #pragma unroll
  for (int off = 1; off < 512; off <<= 1){
    int tmp = (t >= off) ? s[t - off] : 0;
    __syncthreads();
    s[t] += tmp;
    __syncthreads();
  }
  if (t < nblocks) bsum[t] = s[t] - v;
}

__global__ void k_scanC(const int* __restrict__ partial, const int* __restrict__ bsum,
                        int* __restrict__ ptr, int* __restrict__ cursor){
  int i = blockIdx.x * 256 + threadIdx.x;
  if (i < N_N){
    int p = partial[i] + bsum[blockIdx.x];
    ptr[i] = p; cursor[i] = p;
  }
  if (i == 0) ptr[N_N] = N_E;
}

// fill sorted edge structs {src, w} — one 8B store per edge
__global__ void k_fill(const int* __restrict__ src, const int* __restrict__ dst,
                       const float* __restrict__ w, int* __restrict__ cursor,
                       int2* __restrict__ edge8){
  int e = blockIdx.x * 256 + threadIdx.x;
  if (e < N_E){
    int d = dst[e], s = src[e];
    int slot = atomicAdd(&cursor[d], 1);
    edge8[slot] = make_int2(s, __float_as_int(w[e]));
  }
}

// per-node segment sum of w -> deg -> dis, nself (no atomics)
__global__ void k_dis(const int* __restrict__ ptr, const int2* __restrict__ edge8,
                      float* __restrict__ dis, float* __restrict__ nself){
  int i = blockIdx.x * 256 + threadIdx.x;
  if (i >= N_N) return;
  int e0 = ptr[i], e1 = ptr[i + 1];
  float d = 1.0f;                 // self-loop weight
  for (int e = e0; e < e1; ++e) d += __int_as_float(edge8[e].y);
  float r = d > 0.f ? rsqrtf(d) : 0.f;
  dis[i] = r;
  nself[i] = r * r;
}

// rewrite struct w field in-place: ne = dis[src] * w * dis[node]
__global__ void k_ne(const int* __restrict__ ptr, const float* __restrict__ dis,
                     int2* __restrict__ edge8){
  int i = blockIdx.x * 256 + threadIdx.x;
  if (i >= N_N) return;
  float di = dis[i];
  int e0 = ptr[i], e1 = ptr[i + 1];
  for (int e = e0; e < e1; ++e){
    int2 v = edge8[e];
    float ne = dis[v.x] * __int_as_float(v.y) * di;
    ((float*)&edge8[e])[1] = ne;
  }
}

// ---------------- GEMM: H = X @ W, X: nrows x 128, W: 128 x 128 ----------------
__global__ __launch_bounds__(256) void k_gemm(const float* __restrict__ X,
                                              const float* __restrict__ W,
                                              float* __restrict__ H, int nrows){
  __shared__ float lA[64][33];
  __shared__ float lW[32][128];
  int tid = threadIdx.x;
  int row0 = blockIdx.x * 64;
  int tx = tid & 15;
  int ty = tid >> 4;

  float acc[4][8];
  #pragma unroll
  for (int i = 0; i < 4; ++i)
    #pragma unroll
    for (int j = 0; j < 8; ++j) acc[i][j] = 0.f;

  for (int kc = 0; kc < 128; kc += 32){
    #pragma unroll
    for (int it = 0; it < 2; ++it){
      int idx = tid + it * 256;
      int r = idx >> 3;
      int c4 = (idx & 7) * 4;
      float4 v = make_float4(0.f, 0.f, 0.f, 0.f);
      int gr = row0 + r;
      if (gr < nrows) v = *(const float4*)(X + (size_t)gr * HID + kc + c4);
      lA[r][c4 + 0] = v.x; lA[r][c4 + 1] = v.y;
      lA[r][c4 + 2] = v.z; lA[r][c4 + 3] = v.w;
    }
    #pragma unroll
    for (int it = 0; it < 4; ++it){
      int idx = tid + it * 256;
      int r = idx >> 5;
      int c4 = (idx & 31) * 4;
      *(float4*)&lW[r][c4] = *(const float4*)(W + (size_t)(kc + r) * HID + c4);
    }
    __syncthreads();
    #pragma unroll
    for (int k = 0; k < 32; ++k){
      float4 w0 = *(float4*)&lW[k][tx * 8];
      float4 w1 = *(float4*)&lW[k][tx * 8 + 4];
      #pragma unroll
      for (int i = 0; i < 4; ++i){
        float a = lA[ty * 4 + i][k];
        acc[i][0] += a * w0.x; acc[i][1] += a * w0.y;
        acc[i][2] += a * w0.z; acc[i][3] += a * w0.w;
        acc[i][4] += a * w1.x; acc[i][5] += a * w1.y;
        acc[i][6] += a * w1.z; acc[i][7] += a * w1.w;
      }
    }
    __syncthreads();
  }
  #pragma unroll
  for (int i = 0; i < 4; ++i){
    int gr = row0 + ty * 4 + i;
    if (gr < nrows){
      float* o = H + (size_t)gr * HID + tx * 8;
      *(float4*)o       = make_float4(acc[i][0], acc[i][1], acc[i][2], acc[i][3]);
      *(float4*)(o + 4) = make_float4(acc[i][4], acc[i][5], acc[i][6], acc[i][7]);
    }
  }
}

// ---------------- gather aggregation (no atomics) ----------------
__global__ __launch_bounds__(256) void k_gather(const int* __restrict__ ptr,
                                                const int2* __restrict__ edge8,
                                                const float* __restrict__ h,
                                                const float* __restrict__ nself,
                                                const float* __restrict__ bias,
                                                float* __restrict__ agg){
  int t = blockIdx.x * 256 + threadIdx.x;
  int node = t >> 5;
  if (node >= N_N) return;
  int lane = t & 31;
  const float4* h4 = (const float4*)h;
  float ns = nself[node];
  float4 hv = h4[(size_t)node * 32 + lane];
  float4 bv = ((const float4*)bias)[lane];
  float4 acc;
  acc.x = ns * hv.x + bv.x; acc.y = ns * hv.y + bv.y;
  acc.z = ns * hv.z + bv.z; acc.w = ns * hv.w + bv.w;
  int e0 = ptr[node], e1 = ptr[node + 1];
  for (int e = e0; e < e1; ++e){
    int2 ev = edge8[e];
    int s = ev.x;
    float nv = __int_as_float(ev.y);
    float4 sv = h4[(size_t)s * 32 + lane];
    acc.x += nv * sv.x; acc.y += nv * sv.y;
    acc.z += nv * sv.z; acc.w += nv * sv.w;
  }
  ((float4*)agg)[(size_t)node * 32 + lane] = acc;
}

// ---------------- GraphNorm (single-pass stats) ----------------

__global__ void k_zero2(float* __restrict__ a, float* __restrict__ b){
  int i = blockIdx.x * 256 + threadIdx.x;
  if (i < N_G * HID){ a[i] = 0.f; b[i] = 0.f; }
}

__global__ __launch_bounds__(128) void k_gstat(const float* __restrict__ agg,
                                               const int* __restrict__ bp,
                                               float* __restrict__ sum,
                                               float* __restrict__ sumsq){
  int f = threadIdx.x;
  int r0 = blockIdx.x * 64;
  int r1 = min(r0 + 64, N_N);
  int curg = bp[r0];
  float s = 0.f, s2 = 0.f;
  for (int r = r0; r < r1; ++r){
    int g = bp[r];
    if (g != curg){
      atomicAdd(&sum[curg * HID + f], s);
      atomicAdd(&sumsq[curg * HID + f], s2);
      s = 0.f; s2 = 0.f; curg = g;
    }
    float v = agg[(size_t)r * HID + f];
    s += v; s2 += v * v;
  }
  atomicAdd(&sum[curg * HID + f], s);
  atomicAdd(&sumsq[curg * HID + f], s2);
}

__global__ void k_finstat(const float* __restrict__ sum, const float* __restrict__ sumsq,
                          const float* __restrict__ counts, const float* __restrict__ alpha,
                          float* __restrict__ mean, float* __restrict__ rstd){
  int i = blockIdx.x * 256 + threadIdx.x;
  if (i >= N_G * HID) return;
  int f = i & (HID - 1);
  float c = counts[i >> 7];
  float inv = c > 0.f ? 1.0f / c : 0.f;
  float m = sum[i] * inv;
  float ex2 = sumsq[i] * inv;
  float al = alpha[f];
  float var = ex2 - m * m * al * (2.0f - al);
  mean[i] = m;
  rstd[i] = rsqrtf(var + EPSF);
}

__global__ void k_out(const float* __restrict__ agg, const int* __restrict__ bp,
                      const float* __restrict__ mean, const float* __restrict__ rstd,
                      const float* __restrict__ alpha, const float* __restrict__ gw,
                      const float* __restrict__ gb, float* __restrict__ out){
  int idx = blockIdx.x * 256 + threadIdx.x;
  if (idx >= N_N * 32) return;
  int i = idx >> 5, q = idx & 31;
  int g = bp[i];
  float4 a  = ((const float4*)agg)[idx];
  float4 m  = ((const float4*)mean)[g * 32 + q];
  float4 r  = ((const float4*)rstd)[g * 32 + q];
  float4 al = ((const float4*)alpha)[q];
  float4 wv = ((const float4*)gw)[q];
  float4 bv = ((const float4*)gb)[q];
  float4 o;
  o.x = fmaxf(wv.x * (a.x - al.x * m.x) * r.x + bv.x, 0.f);
  o.y = fmaxf(wv.y * (a.y - al.y * m.y) * r.y + bv.y, 0.f);
  o.z = fmaxf(wv.z * (a.z - al.z * m.z) * r.z + bv.z, 0.f);
  o.w = fmaxf(wv.w * (a.w - al.w * m.w) * r.w + bv.w, 0.f);
  ((float4*)out)[idx] = o;
}

// ---------------- launch ----------------

extern "C" void kernel_launch(void* const* d_in, const int* in_sizes, int n_in,
                              void* d_out, int out_size, void* d_ws, size_t ws_size,
                              hipStream_t stream){
  const float* node0 = (const float*)d_in[0];
  const int*   eidx  = (const int*)d_in[1];
  const float* eattr = (const float*)d_in[2];
  const int*   bp    = (const int*)d_in[3];
  const float* W     = (const float*)d_in[4];
  const float* bias  = (const float*)d_in[5];
  const float* gw    = (const float*)d_in[6];
  const float* gb    = (const float*)d_in[7];
  const float* ga    = (const float*)d_in[8];
  float* out = (float*)d_out;
  const int* src = eidx;
  const int* dst = eidx + N_E;

  char* p = (char*)d_ws;
  auto carve = [&](size_t nbytes) -> char* {
    char* q = p; p += (nbytes + 255) & ~(size_t)255; return q;
  };
  float* dis    = (float*)carve((size_t)N_N * 4);
  float* nself  = (float*)carve((size_t)N_N * 4);
  float* counts = (float*)carve((size_t)N_G * 4);
  int*   degi   = (int*)  carve((size_t)N_N * 4);
  int*   partial= (int*)  carve((size_t)N_N * 4);
  int*   bsum   = (int*)  carve((size_t)512 * 4);
  int*   ptr    = (int*)  carve((size_t)(N_N + 1) * 4);
  int*   cursor = (int*)  carve((size_t)N_N * 4);
  int2*  edge8  = (int2*) carve((size_t)N_E * 8);
  float* h      = (float*)carve((size_t)N_N * HID * 4);
  float* agg    = (float*)carve((size_t)N_N * HID * 4);
  float* mean   = (float*)carve((size_t)N_G * HID * 4);
  float* rstd   = (float*)carve((size_t)N_G * HID * 4);
  float* sum    = (float*)carve((size_t)N_G * HID * 4);
  float* sumsq  = (float*)carve((size_t)N_G * HID * 4);

  int nblocks = ceil_div(N_N, 256);   // 391

  k_init  <<<nblocks, 256, 0, stream>>>(degi, counts);
  k_cnt   <<<ceil_div(N_E, 256), 256, 0, stream>>>(dst, degi);
  k_counts<<<ceil_div(N_N, 32 * 256), 256, 0, stream>>>(bp, counts);
  k_scanA <<<nblocks, 256, 0, stream>>>(degi, partial, bsum);
  k_scanB <<<1, 512, 0, stream>>>(bsum, nblocks);
  k_scanC <<<nblocks, 256, 0, stream>>>(partial, bsum, ptr, cursor);
  k_fill  <<<ceil_div(N_E, 256), 256, 0, stream>>>(src, dst, eattr, cursor, edge8);
  k_dis   <<<nblocks, 256, 0, stream>>>(ptr, edge8, dis, nself);
  k_ne    <<<nblocks, 256, 0, stream>>>(ptr, dis, edge8);

  for (int l = 0; l < 3; ++l){
    const float* X = (l == 0) ? node0 : out;
    k_gemm   <<<ceil_div(N_N, 64), 256, 0, stream>>>(X, W + (size_t)l * HID * HID, h, N_N);
    k_gather <<<ceil_div(N_N * 32, 256), 256, 0, stream>>>(ptr, edge8, h, nself,
                 bias + l * HID, agg);
    k_zero2  <<<ceil_div(N_G * HID, 256), 256, 0, stream>>>(sum, sumsq);
    k_gstat  <<<ceil_div(N_N, 64), 128, 0, stream>>>(agg, bp, sum, sumsq);
    k_finstat<<<ceil_div(N_G * HID, 256), 256, 0, stream>>>(sum, sumsq, counts,
                 ga + l * HID, mean, rstd);
    k_out    <<<ceil_div(N_N * 32, 256), 256, 0, stream>>>(agg, bp, mean, rstd,
                 ga + l * HID, gw + l * HID, gb + l * HID, out);
  }
}

// Round 5
// 923.888 us; speedup vs baseline: 9.7854x; 1.0731x over previous
//
#include <hip/hip_runtime.h>
#include <cstdint>

#define N_N 100000
#define N_E 1600000
#define HID 128
#define N_G 100
#define EPSF 1e-5f

static inline int ceil_div(int a, int b){ return (a + b - 1) / b; }

__device__ inline float bf2f(unsigned short u){
  return __uint_as_float(((unsigned int)u) << 16);
}
__device__ inline unsigned short f2bf(float f){
  unsigned int u = __float_as_uint(f);
  unsigned int r = u + 0x7fffu + ((u >> 16) & 1u);   // round-to-nearest-even
  return (unsigned short)(r >> 16);
}

// ---------------- preprocessing ----------------

__global__ void k_init(int* __restrict__ degi, float* __restrict__ counts){
  int i = blockIdx.x * 256 + threadIdx.x;
  if (i < N_N) degi[i] = 0;
  if (i < N_G) counts[i] = 0.0f;
}

__global__ void k_cnt(const int* __restrict__ dst, int* __restrict__ degi){
  int e = blockIdx.x * 256 + threadIdx.x;
  if (e < N_E) atomicAdd(&degi[dst[e]], 1);
}

__global__ void k_counts(const int* __restrict__ bp, float* __restrict__ counts){
  int t = blockIdx.x * 256 + threadIdx.x;
  int r0 = t * 32;
  if (r0 >= N_N) return;
  int r1 = min(r0 + 32, N_N);
  int curg = bp[r0];
  float acc = 0.f;
  for (int r = r0; r < r1; ++r){
    int g = bp[r];
    if (g != curg){ atomicAdd(&counts[curg], acc); acc = 0.f; curg = g; }
    acc += 1.0f;
  }
  atomicAdd(&counts[curg], acc);
}

// ---------------- CSR build ----------------

__global__ __launch_bounds__(256) void k_scanA(const int* __restrict__ degi,
                                               int* __restrict__ partial,
                                               int* __restrict__ bsum){
  __shared__ int s[256];
  int t = threadIdx.x;
  int i = blockIdx.x * 256 + t;
  int v = (i < N_N) ? degi[i] : 0;
  s[t] = v; __syncthreads();
  #pragma unroll
  for (int off = 1; off < 256; off <<= 1){
    int tmp = (t >= off) ? s[t - off] : 0;
    __syncthreads();
    s[t] += tmp;
    __syncthreads();
  }
  if (i < N_N) partial[i] = s[t] - v;
  if (t == 255) bsum[blockIdx.x] = s[255];
}

__global__ __launch_bounds__(512) void k_scanB(int* __restrict__ bsum, int nblocks){
  __shared__ int s[512];
  int t = threadIdx.x;
  int v = (t < nblocks) ? bsum[t] : 0;
  s[t] = v; __syncthreads();
  #pragma unroll
  for (int off = 1; off < 512; off <<= 1){
    int tmp = (t >= off) ? s[t - off] : 0;
    __syncthreads();
    s[t] += tmp;
    __syncthreads();
  }
  if (t < nblocks) bsum[t] = s[t] - v;
}

__global__ void k_scanC(const int* __restrict__ partial, const int* __restrict__ bsum,
                        int* __restrict__ ptr, int* __restrict__ cursor){
  int i = blockIdx.x * 256 + threadIdx.x;
  if (i < N_N){
    int p = partial[i] + bsum[blockIdx.x];
    ptr[i] = p; cursor[i] = p;
  }
  if (i == 0) ptr[N_N] = N_E;
}

__global__ void k_fill(const int* __restrict__ src, const int* __restrict__ dst,
                       const float* __restrict__ w, int* __restrict__ cursor,
                       int2* __restrict__ edge8){
  int e = blockIdx.x * 256 + threadIdx.x;
  if (e < N_E){
    int d = dst[e], s = src[e];
    int slot = atomicAdd(&cursor[d], 1);
    edge8[slot] = make_int2(s, __float_as_int(w[e]));
  }
}

__global__ void k_dis(const int* __restrict__ ptr, const int2* __restrict__ edge8,
                      float* __restrict__ dis, float* __restrict__ nself){
  int i = blockIdx.x * 256 + threadIdx.x;
  if (i >= N_N) return;
  int e0 = ptr[i], e1 = ptr[i + 1];
  float d = 1.0f;
  for (int e = e0; e < e1; ++e) d += __int_as_float(edge8[e].y);
  float r = d > 0.f ? rsqrtf(d) : 0.f;
  dis[i] = r;
  nself[i] = r * r;
}

__global__ void k_ne(const int* __restrict__ ptr, const float* __restrict__ dis,
                     int2* __restrict__ edge8){
  int i = blockIdx.x * 256 + threadIdx.x;
  if (i >= N_N) return;
  float di = dis[i];
  int e0 = ptr[i], e1 = ptr[i + 1];
  for (int e = e0; e < e1; ++e){
    int2 v = edge8[e];
    float ne = dis[v.x] * __int_as_float(v.y) * di;
    ((float*)&edge8[e])[1] = ne;
  }
}

// ---------------- GEMM: H = X @ W (fp32 math, bf16 output) ----------------
__global__ __launch_bounds__(256) void k_gemm(const float* __restrict__ X,
                                              const float* __restrict__ W,
                                              unsigned short* __restrict__ Hb, int nrows){
  __shared__ float lA[64][33];
  __shared__ float lW[32][128];
  int tid = threadIdx.x;
  int row0 = blockIdx.x * 64;
  int tx = tid & 15;
  int ty = tid >> 4;

  float acc[4][8];
  #pragma unroll
  for (int i = 0; i < 4; ++i)
    #pragma unroll
    for (int j = 0; j < 8; ++j) acc[i][j] = 0.f;

  for (int kc = 0; kc < 128; kc += 32){
    #pragma unroll
    for (int it = 0; it < 2; ++it){
      int idx = tid + it * 256;
      int r = idx >> 3;
      int c4 = (idx & 7) * 4;
      float4 v = make_float4(0.f, 0.f, 0.f, 0.f);
      int gr = row0 + r;
      if (gr < nrows) v = *(const float4*)(X + (size_t)gr * HID + kc + c4);
      lA[r][c4 + 0] = v.x; lA[r][c4 + 1] = v.y;
      lA[r][c4 + 2] = v.z; lA[r][c4 + 3] = v.w;
    }
    #pragma unroll
    for (int it = 0; it < 4; ++it){
      int idx = tid + it * 256;
      int r = idx >> 5;
      int c4 = (idx & 31) * 4;
      *(float4*)&lW[r][c4] = *(const float4*)(W + (size_t)(kc + r) * HID + c4);
    }
    __syncthreads();
    #pragma unroll
    for (int k = 0; k < 32; ++k){
      float4 w0 = *(float4*)&lW[k][tx * 8];
      float4 w1 = *(float4*)&lW[k][tx * 8 + 4];
      #pragma unroll
      for (int i = 0; i < 4; ++i){
        float a = lA[ty * 4 + i][k];
        acc[i][0] += a * w0.x; acc[i][1] += a * w0.y;
        acc[i][2] += a * w0.z; acc[i][3] += a * w0.w;
        acc[i][4] += a * w1.x; acc[i][5] += a * w1.y;
        acc[i][6] += a * w1.z; acc[i][7] += a * w1.w;
      }
    }
    __syncthreads();
  }
  #pragma unroll
  for (int i = 0; i < 4; ++i){
    int gr = row0 + ty * 4 + i;
    if (gr < nrows){
      unsigned short pk[8];
      #pragma unroll
      for (int j = 0; j < 8; ++j) pk[j] = f2bf(acc[i][j]);
      // 8 ushorts = 16B aligned store
      *(uint4*)(Hb + (size_t)gr * HID + tx * 8) = *(const uint4*)pk;
    }
  }
}

// ---------------- gather aggregation (bf16 h rows, fp32 accumulate) ----------------
__global__ __launch_bounds__(256) void k_gather(const int* __restrict__ ptr,
                                                const int2* __restrict__ edge8,
                                                const unsigned short* __restrict__ Hb,
                                                const float* __restrict__ nself,
                                                const float* __restrict__ bias,
                                                float* __restrict__ agg){
  int t = blockIdx.x * 256 + threadIdx.x;
  int node = t >> 5;
  if (node >= N_N) return;
  int lane = t & 31;
  const ushort4* h4 = (const ushort4*)Hb;   // 32 ushort4 per row
  float ns = nself[node];
  ushort4 hu = h4[(size_t)node * 32 + lane];
  float4 bv = ((const float4*)bias)[lane];
  float4 acc;
  acc.x = ns * bf2f(hu.x) + bv.x; acc.y = ns * bf2f(hu.y) + bv.y;
  acc.z = ns * bf2f(hu.z) + bv.z; acc.w = ns * bf2f(hu.w) + bv.w;
  int e0 = ptr[node], e1 = ptr[node + 1];
  for (int e = e0; e < e1; ++e){
    int2 ev = edge8[e];
    int s = ev.x;
    float nv = __int_as_float(ev.y);
    ushort4 su = h4[(size_t)s * 32 + lane];
    acc.x += nv * bf2f(su.x); acc.y += nv * bf2f(su.y);
    acc.z += nv * bf2f(su.z); acc.w += nv * bf2f(su.w);
  }
  ((float4*)agg)[(size_t)node * 32 + lane] = acc;
}

// ---------------- GraphNorm (single-pass stats) ----------------

__global__ void k_zero2(float* __restrict__ a, float* __restrict__ b){
  int i = blockIdx.x * 256 + threadIdx.x;
  if (i < N_G * HID){ a[i] = 0.f; b[i] = 0.f; }
}

__global__ __launch_bounds__(128) void k_gstat(const float* __restrict__ agg,
                                               const int* __restrict__ bp,
                                               float* __restrict__ sum,
                                               float* __restrict__ sumsq){
  int f = threadIdx.x;
  int r0 = blockIdx.x * 64;
  int r1 = min(r0 + 64, N_N);
  int curg = bp[r0];
  float s = 0.f, s2 = 0.f;
  for (int r = r0; r < r1; ++r){
    int g = bp[r];
    if (g != curg){
      atomicAdd(&sum[curg * HID + f], s);
      atomicAdd(&sumsq[curg * HID + f], s2);
      s = 0.f; s2 = 0.f; curg = g;
    }
    float v = agg[(size_t)r * HID + f];
    s += v; s2 += v * v;
  }
  atomicAdd(&sum[curg * HID + f], s);
  atomicAdd(&sumsq[curg * HID + f], s2);
}

__global__ void k_finstat(const float* __restrict__ sum, const float* __restrict__ sumsq,
                          const float* __restrict__ counts, const float* __restrict__ alpha,
                          float* __restrict__ mean, float* __restrict__ rstd){
  int i = blockIdx.x * 256 + threadIdx.x;
  if (i >= N_G * HID) return;
  int f = i & (HID - 1);
  float c = counts[i >> 7];
  float inv = c > 0.f ? 1.0f / c : 0.f;
  float m = sum[i] * inv;
  float ex2 = sumsq[i] * inv;
  float al = alpha[f];
  float var = ex2 - m * m * al * (2.0f - al);
  mean[i] = m;
  rstd[i] = rsqrtf(var + EPSF);
}

__global__ void k_out(const float* __restrict__ agg, const int* __restrict__ bp,
                      const float* __restrict__ mean, const float* __restrict__ rstd,
                      const float* __restrict__ alpha, const float* __restrict__ gw,
                      const float* __restrict__ gb, float* __restrict__ out){
  int idx = blockIdx.x * 256 + threadIdx.x;
  if (idx >= N_N * 32) return;
  int i = idx >> 5, q = idx & 31;
  int g = bp[i];
  float4 a  = ((const float4*)agg)[idx];
  float4 m  = ((const float4*)mean)[g * 32 + q];
  float4 r  = ((const float4*)rstd)[g * 32 + q];
  float4 al = ((const float4*)alpha)[q];
  float4 wv = ((const float4*)gw)[q];
  float4 bv = ((const float4*)gb)[q];
  float4 o;
  o.x = fmaxf(wv.x * (a.x - al.x * m.x) * r.x + bv.x, 0.f);
  o.y = fmaxf(wv.y * (a.y - al.y * m.y) * r.y + bv.y, 0.f);
  o.z = fmaxf(wv.z * (a.z - al.z * m.z) * r.z + bv.z, 0.f);
  o.w = fmaxf(wv.w * (a.w - al.w * m.w) * r.w + bv.w, 0.f);
  ((float4*)out)[idx] = o;
}

// ---------------- launch ----------------

extern "C" void kernel_launch(void* const* d_in, const int* in_sizes, int n_in,
                              void* d_out, int out_size, void* d_ws, size_t ws_size,
                              hipStream_t stream){
  const float* node0 = (const float*)d_in[0];
  const int*   eidx  = (const int*)d_in[1];
  const float* eattr = (const float*)d_in[2];
  const int*   bp    = (const int*)d_in[3];
  const float* W     = (const float*)d_in[4];
  const float* bias  = (const float*)d_in[5];
  const float* gw    = (const float*)d_in[6];
  const float* gb    = (const float*)d_in[7];
  const float* ga    = (const float*)d_in[8];
  float* out = (float*)d_out;
  const int* src = eidx;
  const int* dst = eidx + N_E;

  char* p = (char*)d_ws;
  auto carve = [&](size_t nbytes) -> char* {
    char* q = p; p += (nbytes + 255) & ~(size_t)255; return q;
  };
  float* dis    = (float*)carve((size_t)N_N * 4);
  float* nself  = (float*)carve((size_t)N_N * 4);
  float* counts = (float*)carve((size_t)N_G * 4);
  int*   degi   = (int*)  carve((size_t)N_N * 4);
  int*   partial= (int*)  carve((size_t)N_N * 4);
  int*   bsum   = (int*)  carve((size_t)512 * 4);
  int*   ptr    = (int*)  carve((size_t)(N_N + 1) * 4);
  int*   cursor = (int*)  carve((size_t)N_N * 4);
  int2*  edge8  = (int2*) carve((size_t)N_E * 8);
  unsigned short* hb = (unsigned short*)carve((size_t)N_N * HID * 2);
  float* agg    = (float*)carve((size_t)N_N * HID * 4);
  float* mean   = (float*)carve((size_t)N_G * HID * 4);
  float* rstd   = (float*)carve((size_t)N_G * HID * 4);
  float* sum    = (float*)carve((size_t)N_G * HID * 4);
  float* sumsq  = (float*)carve((size_t)N_G * HID * 4);

  int nblocks = ceil_div(N_N, 256);   // 391

  k_init  <<<nblocks, 256, 0, stream>>>(degi, counts);
  k_cnt   <<<ceil_div(N_E, 256), 256, 0, stream>>>(dst, degi);
  k_counts<<<ceil_div(N_N, 32 * 256), 256, 0, stream>>>(bp, counts);
  k_scanA <<<nblocks, 256, 0, stream>>>(degi, partial, bsum);
  k_scanB <<<1, 512, 0, stream>>>(bsum, nblocks);
  k_scanC <<<nblocks, 256, 0, stream>>>(partial, bsum, ptr, cursor);
  k_fill  <<<ceil_div(N_E, 256), 256, 0, stream>>>(src, dst, eattr, cursor, edge8);
  k_dis   <<<nblocks, 256, 0, stream>>>(ptr, edge8, dis, nself);
  k_ne    <<<nblocks, 256, 0, stream>>>(ptr, dis, edge8);

  for (int l = 0; l < 3; ++l){
    const float* X = (l == 0) ? node0 : out;
    k_gemm   <<<ceil_div(N_N, 64), 256, 0, stream>>>(X, W + (size_t)l * HID * HID, hb, N_N);
    k_gather <<<ceil_div(N_N * 32, 256), 256, 0, stream>>>(ptr, edge8, hb, nself,
                 bias + l * HID, agg);
    k_zero2  <<<ceil_div(N_G * HID, 256), 256, 0, stream>>>(sum, sumsq);
    k_gstat  <<<ceil_div(N_N, 64), 128, 0, stream>>>(agg, bp, sum, sumsq);
    k_finstat<<<ceil_div(N_G * HID, 256), 256, 0, stream>>>(sum, sumsq, counts,
                 ga + l * HID, mean, rstd);
    k_out    <<<ceil_div(N_N * 32, 256), 256, 0, stream>>>(agg, bp, mean, rstd,
                 ga + l * HID, gw + l * HID, gb + l * HID, out);
  }
}

// Round 6
// 782.768 us; speedup vs baseline: 11.5495x; 1.1803x over previous
//
#include <hip/hip_runtime.h>
#include <cstdint>

#define N_N 100000
#define N_E 1600000
#define HID 128
#define N_G 100
#define EPSF 1e-5f

static inline int ceil_div(int a, int b){ return (a + b - 1) / b; }

typedef __attribute__((ext_vector_type(8))) short bf16x8;
typedef __attribute__((ext_vector_type(4))) float f32x4;

__device__ inline float bf2f(unsigned short u){
  return __uint_as_float(((unsigned int)u) << 16);
}
__device__ inline unsigned short f2bf(float f){
  unsigned int u = __float_as_uint(f);
  unsigned int r = u + 0x7fffu + ((u >> 16) & 1u);   // round-to-nearest-even
  return (unsigned short)(r >> 16);
}

// ---------------- preprocessing ----------------

__global__ void k_init(int* __restrict__ degi, float* __restrict__ counts){
  int i = blockIdx.x * 256 + threadIdx.x;
  if (i < N_N) degi[i] = 0;
  if (i < N_G) counts[i] = 0.0f;
}

// histogram + per-edge rank (atomic return value) — rank write is coalesced
__global__ void k_cnt(const int* __restrict__ dst, int* __restrict__ degi,
                      int* __restrict__ rank){
  int e = blockIdx.x * 256 + threadIdx.x;
  if (e < N_E) rank[e] = atomicAdd(&degi[dst[e]], 1);
}

__global__ void k_counts(const int* __restrict__ bp, float* __restrict__ counts){
  int t = blockIdx.x * 256 + threadIdx.x;
  int r0 = t * 32;
  if (r0 >= N_N) return;
  int r1 = min(r0 + 32, N_N);
  int curg = bp[r0];
  float acc = 0.f;
  for (int r = r0; r < r1; ++r){
    int g = bp[r];
    if (g != curg){ atomicAdd(&counts[curg], acc); acc = 0.f; curg = g; }
    acc += 1.0f;
  }
  atomicAdd(&counts[curg], acc);
}

// ---------------- CSR build ----------------

__global__ __launch_bounds__(256) void k_scanA(const int* __restrict__ degi,
                                               int* __restrict__ partial,
                                               int* __restrict__ bsum){
  __shared__ int s[256];
  int t = threadIdx.x;
  int i = blockIdx.x * 256 + t;
  int v = (i < N_N) ? degi[i] : 0;
  s[t] = v; __syncthreads();
  #pragma unroll
  for (int off = 1; off < 256; off <<= 1){
    int tmp = (t >= off) ? s[t - off] : 0;
    __syncthreads();
    s[t] += tmp;
    __syncthreads();
  }
  if (i < N_N) partial[i] = s[t] - v;
  if (t == 255) bsum[blockIdx.x] = s[255];
}

__global__ __launch_bounds__(512) void k_scanB(int* __restrict__ bsum, int nblocks){
  __shared__ int s[512];
  int t = threadIdx.x;
  int v = (t < nblocks) ? bsum[t] : 0;
  s[t] = v; __syncthreads();
  #pragma unroll
  for (int off = 1; off < 512; off <<= 1){
    int tmp = (t >= off) ? s[t - off] : 0;
    __syncthreads();
    s[t] += tmp;
    __syncthreads();
  }
  if (t < nblocks) bsum[t] = s[t] - v;
}

__global__ void k_scanC(const int* __restrict__ partial, const int* __restrict__ bsum,
                        int* __restrict__ ptr){
  int i = blockIdx.x * 256 + threadIdx.x;
  if (i < N_N) ptr[i] = partial[i] + bsum[blockIdx.x];
  if (i == 0) ptr[N_N] = N_E;
}

// fill without atomics: slot = ptr[dst] + rank
__global__ void k_fill(const int* __restrict__ src, const int* __restrict__ dst,
                       const float* __restrict__ w, const int* __restrict__ rank,
                       const int* __restrict__ ptr, int2* __restrict__ edge8){
  int e = blockIdx.x * 256 + threadIdx.x;
  if (e < N_E){
    int d = dst[e];
    int slot = ptr[d] + rank[e];
    edge8[slot] = make_int2(src[e], __float_as_int(w[e]));
  }
}

__global__ void k_dis(const int* __restrict__ ptr, const int2* __restrict__ edge8,
                      float* __restrict__ dis, float* __restrict__ nself){
  int i = blockIdx.x * 256 + threadIdx.x;
  if (i >= N_N) return;
  int e0 = ptr[i], e1 = ptr[i + 1];
  float d = 1.0f;
  for (int e = e0; e < e1; ++e) d += __int_as_float(edge8[e].y);
  float r = d > 0.f ? rsqrtf(d) : 0.f;
  dis[i] = r;
  nself[i] = r * r;
}

__global__ void k_ne(const int* __restrict__ ptr, const float* __restrict__ dis,
                     int2* __restrict__ edge8){
  int i = blockIdx.x * 256 + threadIdx.x;
  if (i >= N_N) return;
  float di = dis[i];
  int e0 = ptr[i], e1 = ptr[i + 1];
  for (int e = e0; e < e1; ++e){
    int2 v = edge8[e];
    float ne = dis[v.x] * __int_as_float(v.y) * di;
    ((float*)&edge8[e])[1] = ne;
  }
}

// ---------------- W -> bf16 transposed (per layer, 128x128) ----------------
__global__ void k_wt(const float* __restrict__ W, unsigned short* __restrict__ Wt){
  int i = blockIdx.x * 256 + threadIdx.x;   // i = n*128 + k (output-ordered)
  if (i >= HID * HID) return;
  int n = i >> 7, k = i & 127;
  Wt[i] = f2bf(W[k * HID + n]);
}

// ---------------- GEMM via MFMA: H = X @ W (bf16 in, fp32 acc, bf16 out) ------
// block = 256 threads = 4 waves, 64 rows/block. lA/lB rows padded to 136 ushort.
__global__ __launch_bounds__(256) void k_gemm(const float* __restrict__ X,
                                              const unsigned short* __restrict__ Wt,
                                              unsigned short* __restrict__ Hb, int nrows){
  __shared__ unsigned short lA[64 * 136];    // A[m][k], bf16
  __shared__ unsigned short lB[128 * 136];   // Wt[n][k], bf16
  int tid = threadIdx.x;
  int row0 = blockIdx.x * 64;

  // stage Wt: 128 rows x 128 bf16 = 2048 16B chunks
  #pragma unroll
  for (int i = 0; i < 8; ++i){
    int c = tid + i * 256;
    int r = c >> 4, cc = c & 15;
    *(uint4*)&lB[r * 136 + cc * 8] = ((const uint4*)Wt)[c];
  }
  // stage A: 64 rows x 128 fp32, convert to bf16; 2048 float4 chunks
  #pragma unroll
  for (int i = 0; i < 8; ++i){
    int c = tid + i * 256;
    int r = c >> 5, cc = c & 31;
    int gr = row0 + r;
    float4 v = make_float4(0.f, 0.f, 0.f, 0.f);
    if (gr < nrows) v = *(const float4*)(X + (size_t)gr * HID + cc * 4);
    unsigned short pk[4] = {f2bf(v.x), f2bf(v.y), f2bf(v.z), f2bf(v.w)};
    *(uint2*)&lA[r * 136 + cc * 4] = *(const uint2*)pk;
  }
  __syncthreads();

  int wave = tid >> 6;
  int lane = tid & 63;
  int l16 = lane & 15;
  int quad = lane >> 4;
  int am = wave * 16 + l16;      // A row within block tile

  // a_frags: A[m=am][k = kc*32 + quad*8 + j]
  bf16x8 afr[4];
  #pragma unroll
  for (int kc = 0; kc < 4; ++kc)
    afr[kc] = *(const bf16x8*)&lA[am * 136 + kc * 32 + quad * 8];

  #pragma unroll
  for (int nt = 0; nt < 8; ++nt){
    f32x4 acc = {0.f, 0.f, 0.f, 0.f};
    int bn = nt * 16 + l16;      // output column
    #pragma unroll
    for (int kc = 0; kc < 4; ++kc){
      bf16x8 bfr = *(const bf16x8*)&lB[bn * 136 + kc * 32 + quad * 8];
      acc = __builtin_amdgcn_mfma_f32_16x16x32_bf16(afr[kc], bfr, acc, 0, 0, 0);
    }
    // C/D: col = lane&15, row = quad*4 + reg
    int gr = row0 + wave * 16 + quad * 4;
    #pragma unroll
    for (int r = 0; r < 4; ++r){
      if (gr + r < nrows)
        Hb[(size_t)(gr + r) * HID + nt * 16 + l16] = f2bf(acc[r]);
    }
  }
}

// ---------------- gather aggregation (bf16 h rows, fp32 accumulate) ----------------
__global__ __launch_bounds__(256) void k_gather(const int* __restrict__ ptr,
                                                const int2* __restrict__ edge8,
                                                const unsigned short* __restrict__ Hb,
                                                const float* __restrict__ nself,
                                                const float* __restrict__ bias,
                                                float* __restrict__ agg){
  int t = blockIdx.x * 256 + threadIdx.x;
  int node = t >> 5;
  if (node >= N_N) return;
  int lane = t & 31;
  const ushort4* h4 = (const ushort4*)Hb;
  float ns = nself[node];
  ushort4 hu = h4[(size_t)node * 32 + lane];
  float4 bv = ((const float4*)bias)[lane];
  float4 acc;
  acc.x = ns * bf2f(hu.x) + bv.x; acc.y = ns * bf2f(hu.y) + bv.y;
  acc.z = ns * bf2f(hu.z) + bv.z; acc.w = ns * bf2f(hu.w) + bv.w;
  int e0 = ptr[node], e1 = ptr[node + 1];
  for (int e = e0; e < e1; ++e){
    int2 ev = edge8[e];
    int s = ev.x;
    float nv = __int_as_float(ev.y);
    ushort4 su = h4[(size_t)s * 32 + lane];
    acc.x += nv * bf2f(su.x); acc.y += nv * bf2f(su.y);
    acc.z += nv * bf2f(su.z); acc.w += nv * bf2f(su.w);
  }
  ((float4*)agg)[(size_t)node * 32 + lane] = acc;
}

// ---------------- GraphNorm ----------------

__global__ void k_zero2(float* __restrict__ a, float* __restrict__ b){
  int i = blockIdx.x * 256 + threadIdx.x;
  if (i < N_G * HID){ a[i] = 0.f; b[i] = 0.f; }
}

__global__ __launch_bounds__(128) void k_gstat(const float* __restrict__ agg,
                                               const int* __restrict__ bp,
                                               float* __restrict__ sum,
                                               float* __restrict__ sumsq){
  int f = threadIdx.x;
  int r0 = blockIdx.x * 64;
  int r1 = min(r0 + 64, N_N);
  int curg = bp[r0];
  float s = 0.f, s2 = 0.f;
  for (int r = r0; r < r1; ++r){
    int g = bp[r];
    if (g != curg){
      atomicAdd(&sum[curg * HID + f], s);
      atomicAdd(&sumsq[curg * HID + f], s2);
      s = 0.f; s2 = 0.f; curg = g;
    }
    float v = agg[(size_t)r * HID + f];
    s += v; s2 += v * v;
  }
  atomicAdd(&sum[curg * HID + f], s);
  atomicAdd(&sumsq[curg * HID + f], s2);
}

__global__ void k_finstat(const float* __restrict__ sum, const float* __restrict__ sumsq,
                          const float* __restrict__ counts, const float* __restrict__ alpha,
                          float* __restrict__ mean, float* __restrict__ rstd){
  int i = blockIdx.x * 256 + threadIdx.x;
  if (i >= N_G * HID) return;
  int f = i & (HID - 1);
  float c = counts[i >> 7];
  float inv = c > 0.f ? 1.0f / c : 0.f;
  float m = sum[i] * inv;
  float ex2 = sumsq[i] * inv;
  float al = alpha[f];
  float var = ex2 - m * m * al * (2.0f - al);
  mean[i] = m;
  rstd[i] = rsqrtf(var + EPSF);
}

__global__ void k_out(const float* __restrict__ agg, const int* __restrict__ bp,
                      const float* __restrict__ mean, const float* __restrict__ rstd,
                      const float* __restrict__ alpha, const float* __restrict__ gw,
                      const float* __restrict__ gb, float* __restrict__ out){
  int idx = blockIdx.x * 256 + threadIdx.x;
  if (idx >= N_N * 32) return;
  int i = idx >> 5, q = idx & 31;
  int g = bp[i];
  float4 a  = ((const float4*)agg)[idx];
  float4 m  = ((const float4*)mean)[g * 32 + q];
  float4 r  = ((const float4*)rstd)[g * 32 + q];
  float4 al = ((const float4*)alpha)[q];
  float4 wv = ((const float4*)gw)[q];
  float4 bv = ((const float4*)gb)[q];
  float4 o;
  o.x = fmaxf(wv.x * (a.x - al.x * m.x) * r.x + bv.x, 0.f);
  o.y = fmaxf(wv.y * (a.y - al.y * m.y) * r.y + bv.y, 0.f);
  o.z = fmaxf(wv.z * (a.z - al.z * m.z) * r.z + bv.z, 0.f);
  o.w = fmaxf(wv.w * (a.w - al.w * m.w) * r.w + bv.w, 0.f);
  ((float4*)out)[idx] = o;
}

// ---------------- launch ----------------

extern "C" void kernel_launch(void* const* d_in, const int* in_sizes, int n_in,
                              void* d_out, int out_size, void* d_ws, size_t ws_size,
                              hipStream_t stream){
  const float* node0 = (const float*)d_in[0];
  const int*   eidx  = (const int*)d_in[1];
  const float* eattr = (const float*)d_in[2];
  const int*   bp    = (const int*)d_in[3];
  const float* W     = (const float*)d_in[4];
  const float* bias  = (const float*)d_in[5];
  const float* gw    = (const float*)d_in[6];
  const float* gb    = (const float*)d_in[7];
  const float* ga    = (const float*)d_in[8];
  float* out = (float*)d_out;
  const int* src = eidx;
  const int* dst = eidx + N_E;

  char* p = (char*)d_ws;
  auto carve = [&](size_t nbytes) -> char* {
    char* q = p; p += (nbytes + 255) & ~(size_t)255; return q;
  };
  float* dis    = (float*)carve((size_t)N_N * 4);
  float* nself  = (float*)carve((size_t)N_N * 4);
  float* counts = (float*)carve((size_t)N_G * 4);
  int*   degi   = (int*)  carve((size_t)N_N * 4);
  int*   partial= (int*)  carve((size_t)N_N * 4);
  int*   bsum   = (int*)  carve((size_t)512 * 4);
  int*   ptr    = (int*)  carve((size_t)(N_N + 1) * 4);
  int*   rank   = (int*)  carve((size_t)N_E * 4);
  int2*  edge8  = (int2*) carve((size_t)N_E * 8);
  unsigned short* hb = (unsigned short*)carve((size_t)N_N * HID * 2);
  unsigned short* wt = (unsigned short*)carve((size_t)HID * HID * 2);
  float* agg    = (float*)carve((size_t)N_N * HID * 4);
  float* mean   = (float*)carve((size_t)N_G * HID * 4);
  float* rstd   = (float*)carve((size_t)N_G * HID * 4);
  float* sum    = (float*)carve((size_t)N_G * HID * 4);
  float* sumsq  = (float*)carve((size_t)N_G * HID * 4);

  int nblocks = ceil_div(N_N, 256);   // 391

  k_init  <<<nblocks, 256, 0, stream>>>(degi, counts);
  k_cnt   <<<ceil_div(N_E, 256), 256, 0, stream>>>(dst, degi, rank);
  k_counts<<<ceil_div(N_N, 32 * 256), 256, 0, stream>>>(bp, counts);
  k_scanA <<<nblocks, 256, 0, stream>>>(degi, partial, bsum);
  k_scanB <<<1, 512, 0, stream>>>(bsum, nblocks);
  k_scanC <<<nblocks, 256, 0, stream>>>(partial, bsum, ptr);
  k_fill  <<<ceil_div(N_E, 256), 256, 0, stream>>>(src, dst, eattr, rank, ptr, edge8);
  k_dis   <<<nblocks, 256, 0, stream>>>(ptr, edge8, dis, nself);
  k_ne    <<<nblocks, 256, 0, stream>>>(ptr, dis, edge8);

  for (int l = 0; l < 3; ++l){
    const float* X = (l == 0) ? node0 : out;
    k_wt     <<<ceil_div(HID * HID, 256), 256, 0, stream>>>(W + (size_t)l * HID * HID, wt);
    k_gemm   <<<ceil_div(N_N, 64), 256, 0, stream>>>(X, wt, hb, N_N);
    k_gather <<<ceil_div(N_N * 32, 256), 256, 0, stream>>>(ptr, edge8, hb, nself,
                 bias + l * HID, agg);
    k_zero2  <<<ceil_div(N_G * HID, 256), 256, 0, stream>>>(sum, sumsq);
    k_gstat  <<<ceil_div(N_N, 64), 128, 0, stream>>>(agg, bp, sum, sumsq);
    k_finstat<<<ceil_div(N_G * HID, 256), 256, 0, stream>>>(sum, sumsq, counts,
                 ga + l * HID, mean, rstd);
    k_out    <<<ceil_div(N_N * 32, 256), 256, 0, stream>>>(agg, bp, mean, rstd,
                 ga + l * HID, gw + l * HID, gb + l * HID, out);
  }
}

// Round 7
// 646.523 us; speedup vs baseline: 13.9834x; 1.2107x over previous
//
#include <hip/hip_runtime.h>
#include <cstdint>

#define N_N 100000
#define N_E 1600000
#define HID 128
#define N_G 100
#define EPSF 1e-5f

static inline int ceil_div(int a, int b){ return (a + b - 1) / b; }

typedef __attribute__((ext_vector_type(8))) short bf16x8;
typedef __attribute__((ext_vector_type(4))) float f32x4;

__device__ inline float bf2f(unsigned short u){
  return __uint_as_float(((unsigned int)u) << 16);
}
__device__ inline unsigned short f2bf(float f){
  unsigned int u = __float_as_uint(f);
  unsigned int r = u + 0x7fffu + ((u >> 16) & 1u);   // round-to-nearest-even
  return (unsigned short)(r >> 16);
}
// 8 packed bf16 (uint4) -> acc[0..7] += nv * val
__device__ inline void fma8(float* acc, float nv, uint4 u){
  acc[0] += nv * __uint_as_float(u.x << 16);
  acc[1] += nv * __uint_as_float(u.x & 0xffff0000u);
  acc[2] += nv * __uint_as_float(u.y << 16);
  acc[3] += nv * __uint_as_float(u.y & 0xffff0000u);
  acc[4] += nv * __uint_as_float(u.z << 16);
  acc[5] += nv * __uint_as_float(u.z & 0xffff0000u);
  acc[6] += nv * __uint_as_float(u.w << 16);
  acc[7] += nv * __uint_as_float(u.w & 0xffff0000u);
}

// ---------------- preprocessing ----------------

__global__ void k_init(int* __restrict__ degi, float* __restrict__ counts){
  int i = blockIdx.x * 256 + threadIdx.x;
  if (i < N_N) degi[i] = 0;
  if (i < N_G) counts[i] = 0.0f;
}

__global__ void k_cnt(const int* __restrict__ dst, int* __restrict__ degi,
                      int* __restrict__ rank){
  int e = blockIdx.x * 256 + threadIdx.x;
  if (e < N_E) rank[e] = atomicAdd(&degi[dst[e]], 1);
}

__global__ void k_counts(const int* __restrict__ bp, float* __restrict__ counts){
  int t = blockIdx.x * 256 + threadIdx.x;
  int r0 = t * 32;
  if (r0 >= N_N) return;
  int r1 = min(r0 + 32, N_N);
  int curg = bp[r0];
  float acc = 0.f;
  for (int r = r0; r < r1; ++r){
    int g = bp[r];
    if (g != curg){ atomicAdd(&counts[curg], acc); acc = 0.f; curg = g; }
    acc += 1.0f;
  }
  atomicAdd(&counts[curg], acc);
}

// ---------------- CSR build ----------------

__global__ __launch_bounds__(256) void k_scanA(const int* __restrict__ degi,
                                               int* __restrict__ partial,
                                               int* __restrict__ bsum){
  __shared__ int s[256];
  int t = threadIdx.x;
  int i = blockIdx.x * 256 + t;
  int v = (i < N_N) ? degi[i] : 0;
  s[t] = v; __syncthreads();
  #pragma unroll
  for (int off = 1; off < 256; off <<= 1){
    int tmp = (t >= off) ? s[t - off] : 0;
    __syncthreads();
    s[t] += tmp;
    __syncthreads();
  }
  if (i < N_N) partial[i] = s[t] - v;
  if (t == 255) bsum[blockIdx.x] = s[255];
}

__global__ __launch_bounds__(512) void k_scanB(int* __restrict__ bsum, int nblocks){
  __shared__ int s[512];
  int t = threadIdx.x;
  int v = (t < nblocks) ? bsum[t] : 0;
  s[t] = v; __syncthreads();
  #pragma unroll
  for (int off = 1; off < 512; off <<= 1){
    int tmp = (t >= off) ? s[t - off] : 0;
    __syncthreads();
    s[t] += tmp;
    __syncthreads();
  }
  if (t < nblocks) bsum[t] = s[t] - v;
}

__global__ void k_scanC(const int* __restrict__ partial, const int* __restrict__ bsum,
                        int* __restrict__ ptr){
  int i = blockIdx.x * 256 + threadIdx.x;
  if (i < N_N) ptr[i] = partial[i] + bsum[blockIdx.x];
  if (i == 0) ptr[N_N] = N_E;
}

__global__ void k_fill(const int* __restrict__ src, const int* __restrict__ dst,
                       const float* __restrict__ w, const int* __restrict__ rank,
                       const int* __restrict__ ptr, int2* __restrict__ edge8){
  int e = blockIdx.x * 256 + threadIdx.x;
  if (e < N_E){
    int d = dst[e];
    int slot = ptr[d] + rank[e];
    edge8[slot] = make_int2(src[e], __float_as_int(w[e]));
  }
}

__global__ void k_dis(const int* __restrict__ ptr, const int2* __restrict__ edge8,
                      float* __restrict__ dis, float* __restrict__ nself){
  int i = blockIdx.x * 256 + threadIdx.x;
  if (i >= N_N) return;
  int e0 = ptr[i], e1 = ptr[i + 1];
  float d = 1.0f;
  for (int e = e0; e < e1; ++e) d += __int_as_float(edge8[e].y);
  float r = d > 0.f ? rsqrtf(d) : 0.f;
  dis[i] = r;
  nself[i] = r * r;
}

__global__ void k_ne(const int* __restrict__ ptr, const float* __restrict__ dis,
                     int2* __restrict__ edge8){
  int i = blockIdx.x * 256 + threadIdx.x;
  if (i >= N_N) return;
  float di = dis[i];
  int e0 = ptr[i], e1 = ptr[i + 1];
  for (int e = e0; e < e1; ++e){
    int2 v = edge8[e];
    float ne = dis[v.x] * __int_as_float(v.y) * di;
    ((float*)&edge8[e])[1] = ne;
  }
}

// ---------------- W -> bf16 transposed (per layer, 128x128) ----------------
__global__ void k_wt(const float* __restrict__ W, unsigned short* __restrict__ Wt){
  int i = blockIdx.x * 256 + threadIdx.x;   // i = n*128 + k
  if (i >= HID * HID) return;
  int n = i >> 7, k = i & 127;
  Wt[i] = f2bf(W[k * HID + n]);
}

// ---------------- GEMM via MFMA, optional fused GraphNorm+ReLU on input ------
// fused=0: A row = X[gr]. fused=1: A row = relu(gw*(agg-al*mean)*rstd+gb).
__global__ __launch_bounds__(256) void k_gemm(const float* __restrict__ X,
                                              const float* __restrict__ agg,
                                              int fused,
                                              const int* __restrict__ bp,
                                              const float* __restrict__ mean,
                                              const float* __restrict__ rstd,
                                              const float* __restrict__ alpha,
                                              const float* __restrict__ gwv,
                                              const float* __restrict__ gbv,
                                              const unsigned short* __restrict__ Wt,
                                              unsigned short* __restrict__ Hb, int nrows){
  __shared__ unsigned short lA[64 * 136];
  __shared__ unsigned short lB[128 * 136];
  int tid = threadIdx.x;
  int row0 = blockIdx.x * 64;

  #pragma unroll
  for (int i = 0; i < 8; ++i){
    int c = tid + i * 256;
    int r = c >> 4, cc = c & 15;
    *(uint4*)&lB[r * 136 + cc * 8] = ((const uint4*)Wt)[c];
  }
  #pragma unroll
  for (int i = 0; i < 8; ++i){
    int c = tid + i * 256;
    int r = c >> 5, cc = c & 31;
    int gr = row0 + r;
    float4 v = make_float4(0.f, 0.f, 0.f, 0.f);
    if (gr < nrows){
      if (!fused){
        v = *(const float4*)(X + (size_t)gr * HID + cc * 4);
      } else {
        int g = bp[gr];
        float4 a  = *(const float4*)(agg  + (size_t)gr * HID + cc * 4);
        float4 m  = *(const float4*)(mean + g * HID + cc * 4);
        float4 rs = *(const float4*)(rstd + g * HID + cc * 4);
        float4 al = *(const float4*)(alpha + cc * 4);
        float4 wv = *(const float4*)(gwv + cc * 4);
        float4 bv = *(const float4*)(gbv + cc * 4);
        v.x = fmaxf(wv.x * (a.x - al.x * m.x) * rs.x + bv.x, 0.f);
        v.y = fmaxf(wv.y * (a.y - al.y * m.y) * rs.y + bv.y, 0.f);
        v.z = fmaxf(wv.z * (a.z - al.z * m.z) * rs.z + bv.z, 0.f);
        v.w = fmaxf(wv.w * (a.w - al.w * m.w) * rs.w + bv.w, 0.f);
      }
    }
    unsigned short pk[4] = {f2bf(v.x), f2bf(v.y), f2bf(v.z), f2bf(v.w)};
    *(uint2*)&lA[r * 136 + cc * 4] = *(const uint2*)pk;
  }
  __syncthreads();

  int wave = tid >> 6;
  int lane = tid & 63;
  int l16 = lane & 15;
  int quad = lane >> 4;
  int am = wave * 16 + l16;

  bf16x8 afr[4];
  #pragma unroll
  for (int kc = 0; kc < 4; ++kc)
    afr[kc] = *(const bf16x8*)&lA[am * 136 + kc * 32 + quad * 8];

  #pragma unroll
  for (int nt = 0; nt < 8; ++nt){
    f32x4 acc = {0.f, 0.f, 0.f, 0.f};
    int bn = nt * 16 + l16;
    #pragma unroll
    for (int kc = 0; kc < 4; ++kc){
      bf16x8 bfr = *(const bf16x8*)&lB[bn * 136 + kc * 32 + quad * 8];
      acc = __builtin_amdgcn_mfma_f32_16x16x32_bf16(afr[kc], bfr, acc, 0, 0, 0);
    }
    int gr = row0 + wave * 16 + quad * 4;
    #pragma unroll
    for (int r = 0; r < 4; ++r){
      if (gr + r < nrows)
        Hb[(size_t)(gr + r) * HID + nt * 16 + l16] = f2bf(acc[r]);
    }
  }
}

// ---------------- gather aggregation: 16 lanes/node, unroll x4 ----------------
__global__ __launch_bounds__(256) void k_gather(const int* __restrict__ ptr,
                                                const int2* __restrict__ edge8,
                                                const unsigned short* __restrict__ Hb,
                                                const float* __restrict__ nself,
                                                const float* __restrict__ bias,
                                                float* __restrict__ agg){
  int t = blockIdx.x * 256 + threadIdx.x;
  int node = t >> 4;
  if (node >= N_N) return;
  int lane = t & 15;                        // 8 features (16B) per lane
  const uint4* h16 = (const uint4*)Hb;      // 16 uint4 per row
  float ns = nself[node];
  uint4 hu = h16[(size_t)node * 16 + lane];
  float4 b0 = ((const float4*)bias)[lane * 2];
  float4 b1 = ((const float4*)bias)[lane * 2 + 1];
  float acc[8] = {b0.x, b0.y, b0.z, b0.w, b1.x, b1.y, b1.z, b1.w};
  fma8(acc, ns, hu);

  int e0 = ptr[node], e1 = ptr[node + 1];
  int e = e0;
  for (; e + 4 <= e1; e += 4){
    int2 ev0 = edge8[e + 0];
    int2 ev1 = edge8[e + 1];
    int2 ev2 = edge8[e + 2];
    int2 ev3 = edge8[e + 3];
    uint4 r0 = h16[(size_t)ev0.x * 16 + lane];
    uint4 r1 = h16[(size_t)ev1.x * 16 + lane];
    uint4 r2 = h16[(size_t)ev2.x * 16 + lane];
    uint4 r3 = h16[(size_t)ev3.x * 16 + lane];
    fma8(acc, __int_as_float(ev0.y), r0);
    fma8(acc, __int_as_float(ev1.y), r1);
    fma8(acc, __int_as_float(ev2.y), r2);
    fma8(acc, __int_as_float(ev3.y), r3);
  }
  for (; e < e1; ++e){
    int2 ev = edge8[e];
    uint4 r0 = h16[(size_t)ev.x * 16 + lane];
    fma8(acc, __int_as_float(ev.y), r0);
  }
  float4* ap = (float4*)(agg + (size_t)node * HID + lane * 8);
  ap[0] = make_float4(acc[0], acc[1], acc[2], acc[3]);
  ap[1] = make_float4(acc[4], acc[5], acc[6], acc[7]);
}

// ---------------- GraphNorm ----------------

__global__ void k_zero2(float* __restrict__ a, float* __restrict__ b){
  int i = blockIdx.x * 256 + threadIdx.x;
  if (i < N_G * HID){ a[i] = 0.f; b[i] = 0.f; }
}

__global__ __launch_bounds__(128) void k_gstat(const float* __restrict__ agg,
                                               const int* __restrict__ bp,
                                               float* __restrict__ sum,
                                               float* __restrict__ sumsq){
  int f = threadIdx.x;
  int r0 = blockIdx.x * 64;
  int r1 = min(r0 + 64, N_N);
  int curg = bp[r0];
  float s = 0.f, s2 = 0.f;
  for (int r = r0; r < r1; ++r){
    int g = bp[r];
    if (g != curg){
      atomicAdd(&sum[curg * HID + f], s);
      atomicAdd(&sumsq[curg * HID + f], s2);
      s = 0.f; s2 = 0.f; curg = g;
    }
    float v = agg[(size_t)r * HID + f];
    s += v; s2 += v * v;
  }
  atomicAdd(&sum[curg * HID + f], s);
  atomicAdd(&sumsq[curg * HID + f], s2);
}

__global__ void k_finstat(const float* __restrict__ sum, const float* __restrict__ sumsq,
                          const float* __restrict__ counts, const float* __restrict__ alpha,
                          float* __restrict__ mean, float* __restrict__ rstd){
  int i = blockIdx.x * 256 + threadIdx.x;
  if (i >= N_G * HID) return;
  int f = i & (HID - 1);
  float c = counts[i >> 7];
  float inv = c > 0.f ? 1.0f / c : 0.f;
  float m = sum[i] * inv;
  float ex2 = sumsq[i] * inv;
  float al = alpha[f];
  float var = ex2 - m * m * al * (2.0f - al);
  mean[i] = m;
  rstd[i] = rsqrtf(var + EPSF);
}

__global__ void k_out(const float* __restrict__ agg, const int* __restrict__ bp,
                      const float* __restrict__ mean, const float* __restrict__ rstd,
                      const float* __restrict__ alpha, const float* __restrict__ gw,
                      const float* __restrict__ gb, float* __restrict__ out){
  int idx = blockIdx.x * 256 + threadIdx.x;
  if (idx >= N_N * 32) return;
  int i = idx >> 5, q = idx & 31;
  int g = bp[i];
  float4 a  = ((const float4*)agg)[idx];
  float4 m  = ((const float4*)mean)[g * 32 + q];
  float4 r  = ((const float4*)rstd)[g * 32 + q];
  float4 al = ((const float4*)alpha)[q];
  float4 wv = ((const float4*)gw)[q];
  float4 bv = ((const float4*)gb)[q];
  float4 o;
  o.x = fmaxf(wv.x * (a.x - al.x * m.x) * r.x + bv.x, 0.f);
  o.y = fmaxf(wv.y * (a.y - al.y * m.y) * r.y + bv.y, 0.f);
  o.z = fmaxf(wv.z * (a.z - al.z * m.z) * r.z + bv.z, 0.f);
  o.w = fmaxf(wv.w * (a.w - al.w * m.w) * r.w + bv.w, 0.f);
  ((float4*)out)[idx] = o;
}

// ---------------- launch ----------------

extern "C" void kernel_launch(void* const* d_in, const int* in_sizes, int n_in,
                              void* d_out, int out_size, void* d_ws, size_t ws_size,
                              hipStream_t stream){
  const float* node0 = (const float*)d_in[0];
  const int*   eidx  = (const int*)d_in[1];
  const float* eattr = (const float*)d_in[2];
  const int*   bp    = (const int*)d_in[3];
  const float* W     = (const float*)d_in[4];
  const float* bias  = (const float*)d_in[5];
  const float* gw    = (const float*)d_in[6];
  const float* gb    = (const float*)d_in[7];
  const float* ga    = (const float*)d_in[8];
  float* out = (float*)d_out;
  const int* src = eidx;
  const int* dst = eidx + N_E;

  char* p = (char*)d_ws;
  auto carve = [&](size_t nbytes) -> char* {
    char* q = p; p += (nbytes + 255) & ~(size_t)255; return q;
  };
  float* dis    = (float*)carve((size_t)N_N * 4);
  float* nself  = (float*)carve((size_t)N_N * 4);
  float* counts = (float*)carve((size_t)N_G * 4);
  int*   degi   = (int*)  carve((size_t)N_N * 4);
  int*   partial= (int*)  carve((size_t)N_N * 4);
  int*   bsum   = (int*)  carve((size_t)512 * 4);
  int*   ptr    = (int*)  carve((size_t)(N_N + 1) * 4);
  int*   rank   = (int*)  carve((size_t)N_E * 4);
  int2*  edge8  = (int2*) carve((size_t)N_E * 8);
  unsigned short* hb = (unsigned short*)carve((size_t)N_N * HID * 2);
  unsigned short* wt = (unsigned short*)carve((size_t)HID * HID * 2);
  float* agg    = (float*)carve((size_t)N_N * HID * 4);
  float* mean   = (float*)carve((size_t)N_G * HID * 4);
  float* rstd   = (float*)carve((size_t)N_G * HID * 4);
  float* sum    = (float*)carve((size_t)N_G * HID * 4);
  float* sumsq  = (float*)carve((size_t)N_G * HID * 4);

  int nblocks = ceil_div(N_N, 256);   // 391

  k_init  <<<nblocks, 256, 0, stream>>>(degi, counts);
  k_cnt   <<<ceil_div(N_E, 256), 256, 0, stream>>>(dst, degi, rank);
  k_counts<<<ceil_div(N_N, 32 * 256), 256, 0, stream>>>(bp, counts);
  k_scanA <<<nblocks, 256, 0, stream>>>(degi, partial, bsum);
  k_scanB <<<1, 512, 0, stream>>>(bsum, nblocks);
  k_scanC <<<nblocks, 256, 0, stream>>>(partial, bsum, ptr);
  k_fill  <<<ceil_div(N_E, 256), 256, 0, stream>>>(src, dst, eattr, rank, ptr, edge8);
  k_dis   <<<nblocks, 256, 0, stream>>>(ptr, edge8, dis, nself);
  k_ne    <<<nblocks, 256, 0, stream>>>(ptr, dis, edge8);

  for (int l = 0; l < 3; ++l){
    k_wt <<<ceil_div(HID * HID, 256), 256, 0, stream>>>(W + (size_t)l * HID * HID, wt);
    if (l == 0){
      k_gemm <<<ceil_div(N_N, 64), 256, 0, stream>>>(node0, nullptr, 0,
                 nullptr, nullptr, nullptr, nullptr, nullptr, nullptr, wt, hb, N_N);
    } else {
      k_gemm <<<ceil_div(N_N, 64), 256, 0, stream>>>(nullptr, agg, 1,
                 bp, mean, rstd, ga + (l - 1) * HID, gw + (l - 1) * HID,
                 gb + (l - 1) * HID, wt, hb, N_N);
    }
    k_gather <<<ceil_div(N_N * 16, 256), 256, 0, stream>>>(ptr, edge8, hb, nself,
                 bias + l * HID, agg);
    k_zero2  <<<ceil_div(N_G * HID, 256), 256, 0, stream>>>(sum, sumsq);
    k_gstat  <<<ceil_div(N_N, 64), 128, 0, stream>>>(agg, bp, sum, sumsq);
    k_finstat<<<ceil_div(N_G * HID, 256), 256, 0, stream>>>(sum, sumsq, counts,
                 ga + l * HID, mean, rstd);
  }
  k_out <<<ceil_div(N_N * 32, 256), 256, 0, stream>>>(agg, bp, mean, rstd,
             ga + 2 * HID, gw + 2 * HID, gb + 2 * HID, out);
}